// Round 11
// baseline (485.338 us; speedup 1.0000x reference)
//
#include <hip/hip_runtime.h>
#include <hip/hip_fp16.h>

constexpr int kNodes = 50000;
constexpr int kNE    = 800000;            // edges before self loops
constexpr int kFin   = 256;
constexpr int kC     = 32;
constexpr int kH     = 4;
constexpr int kHC    = 128;               // kH * kC
constexpr int kTN    = 16;                // nodes per k_embed block
constexpr int kLWP   = 130;               // padded s_lwT row in k_post (float2-aligned, 2-way alias)
constexpr int kEmbedBlocks = kNodes / kTN;        // 3125
constexpr int kTransBlocks = (kNodes + 31) / 32;  // 1563
constexpr int kHistGS = 256;              // grid-stride hist blocks (4-deep atomic MLP)
constexpr int kReoGS  = 256;              // grid-stride reorder blocks
constexpr int kDegBlocks = (kNodes + 255) / 256;  // 196 (k_prep deg-zero role)
constexpr float kEps   = 1e-5f;
constexpr float kSlope = 0.2f;
constexpr float kL2E   = 1.44269504f;     // log2(e): fold into att so exp is 1 instr
constexpr float kShift2 = 8.0f * 1.44269504f; // softmax-invariant shift (exp2 domain)

typedef _Float16 f16;
typedef _Float16 f16x2 __attribute__((ext_vector_type(2)));
struct alignas(16) h8 { f16x2 v[4]; };    // 8 halves = 16 B

__device__ __forceinline__ float fdot2_(f16x2 a, f16x2 b, float c) {
#if __has_builtin(__builtin_amdgcn_fdot2)
    return __builtin_amdgcn_fdot2(a, b, c, false);
#else
    return fmaf((float)a.x, (float)b.x, fmaf((float)a.y, (float)b.y, c));
#endif
}

// ---- DPP butterfly add: v += partner(v), pure VALU (no DS pipe).
template<int CTRL>
__device__ __forceinline__ float dpp_add(float v) {
    int x = __builtin_amdgcn_update_dpp(0, __float_as_int(v), CTRL, 0xF, 0xF, true);
    return v + __int_as_float(x);
}
// 8-lane sum (head = 8 lanes x 4 features): xor1, xor2, then row_half_mirror.
__device__ __forceinline__ float red8(float p) {
    p = dpp_add<0xB1>(p);
    p = dpp_add<0x4E>(p);
    p = dpp_add<0x141>(p);
    return p;
}

// ---- K0: prep — zero deg (196 blocks) + convert W to fp16 PRE-SWIZZLED
// [i8][c][8] (32 blocks) + zero both layers' stats.
__global__ void __launch_bounds__(256) k_prep(
    unsigned* __restrict__ deg, const float* __restrict__ W, f16* __restrict__ Wh,
    float* __restrict__ stats) {
    int t = threadIdx.x;
    if (blockIdx.x == 0 && t < 4) stats[t] = 0.f;
    if (blockIdx.x < kDegBlocks) {
        int i = blockIdx.x * 256 + t;
        if (i < kNodes) deg[i] = 0u;
        return;
    }
    int i = (blockIdx.x - kDegBlocks) * 256 + t;   // 32 blocks x 256 = 8192 = kFin*kC
    int k = i >> 5, c = i & 31;
    Wh[((k >> 3) * kC + c) * 8 + (k & 7)] = (f16)W[i];
}

// ---- K_A: role-split fused kernel, fp16 operands + v_dot2_f32_f16.
// blocks [0, kHistGS): grid-stride degree histogram, 4-deep batches; the
// atomicAdd RETURN VALUE is the edge's rank within its dst row -> rank[e].
// blocks [kHistGS, +kEmbedBlocks): h0 = relu(node_ln(x @ W_emb + b_emb)); jk = h0.
__global__ void __launch_bounds__(256) k_embed_hist(
    const float* __restrict__ x, const f16* __restrict__ Wh, const float* __restrict__ b,
    const float* __restrict__ lnw, const float* __restrict__ lnb,
    float* __restrict__ h, float* __restrict__ jk,
    const int* __restrict__ dst, int* __restrict__ deg, unsigned short* __restrict__ rank) {
    __shared__ f16 sxh[kTN * kFin];       // 8 KB
    __shared__ f16 sWh[kFin / 8 * kC * 8];// 16 KB, [i8][c] blocks of 8 halves
    int t = threadIdx.x;
    if (blockIdx.x < kHistGS) {           // ---- hist role (grid-stride, 4-deep)
        const int stride = kHistGS * 256;
        int e = blockIdx.x * 256 + t;
        for (; e + 3 * stride < kNE; e += 4 * stride) {
            int d0 = dst[e], d1 = dst[e + stride], d2 = dst[e + 2 * stride], d3 = dst[e + 3 * stride];
            int r0 = atomicAdd(&deg[d0], 1);
            int r1 = atomicAdd(&deg[d1], 1);
            int r2 = atomicAdd(&deg[d2], 1);
            int r3 = atomicAdd(&deg[d3], 1);
            rank[e] = (unsigned short)r0;
            rank[e + stride] = (unsigned short)r1;
            rank[e + 2 * stride] = (unsigned short)r2;
            rank[e + 3 * stride] = (unsigned short)r3;
        }
        for (; e < kNE; e += stride) {
            int d = dst[e];
            rank[e] = (unsigned short)atomicAdd(&deg[d], 1);
        }
        return;
    }
    // ---- embed role
    int n0 = (blockIdx.x - kHistGS) * kTN;       // 50000 = 3125 * 16 exact
    {
        const h8* Wg = (const h8*)Wh;
        h8* sW8 = (h8*)sWh;
        for (int i = t; i < kFin * kC / 8; i += 256) sW8[i] = Wg[i];
    }
    const float2* xg2 = (const float2*)(x + (long)n0 * kFin);
    f16x2* sx2 = (f16x2*)sxh;
    for (int i = t; i < kTN * kFin / 2; i += 256) {
        float2 v = xg2[i];
        f16x2 hv; hv.x = (f16)v.x; hv.y = (f16)v.y;
        sx2[i] = hv;
    }
    __syncthreads();
    int c = t & 31, n2 = t >> 5;          // n2 = 0..7
    const h8* xa = (const h8*)(sxh + n2 * kFin);
    const h8* xb = (const h8*)(sxh + (n2 + 8) * kFin);
    const h8* wr = (const h8*)sWh;        // [i8*kC + c]
    float a0 = 0.f, a0b = 0.f, a1 = 0.f, a1b = 0.f;
    #pragma unroll 8
    for (int i8 = 0; i8 < kFin / 8; ++i8) {
        h8 xv0 = xa[i8];
        h8 xv1 = xb[i8];
        h8 wv  = wr[i8 * kC + c];
        a0  = fdot2_(xv0.v[0], wv.v[0], a0);
        a0b = fdot2_(xv0.v[1], wv.v[1], a0b);
        a0  = fdot2_(xv0.v[2], wv.v[2], a0);
        a0b = fdot2_(xv0.v[3], wv.v[3], a0b);
        a1  = fdot2_(xv1.v[0], wv.v[0], a1);
        a1b = fdot2_(xv1.v[1], wv.v[1], a1b);
        a1  = fdot2_(xv1.v[2], wv.v[2], a1);
        a1b = fdot2_(xv1.v[3], wv.v[3], a1b);
    }
    float acc0 = a0 + a0b, acc1 = a1 + a1b;
    float bc = b[c], lw = lnw[c], lb = lnb[c];
    {
        float y = acc0 + bc;
        float m = y;
        #pragma unroll
        for (int o = 1; o < 32; o <<= 1) m += __shfl_xor(m, o);
        m *= (1.f / kC);
        float xc = y - m, v = xc * xc;
        #pragma unroll
        for (int o = 1; o < 32; o <<= 1) v += __shfl_xor(v, o);
        v *= (1.f / kC);
        float out = fmaxf(xc * rsqrtf(v + kEps) * lw + lb, 0.f);
        int node = n0 + n2;
        h[node * kC + c] = out;
        jk[node * kC + c] = out;
    }
    {
        float y = acc1 + bc;
        float m = y;
        #pragma unroll
        for (int o = 1; o < 32; o <<= 1) m += __shfl_xor(m, o);
        m *= (1.f / kC);
        float xc = y - m, v = xc * xc;
        #pragma unroll
        for (int o = 1; o < 32; o <<= 1) v += __shfl_xor(v, o);
        v *= (1.f / kC);
        float out = fmaxf(xc * rsqrtf(v + kEps) * lw + lb, 0.f);
        int node = n0 + n2 + 8;
        h[node * kC + c] = out;
        jk[node * kC + c] = out;
    }
}

// ---- trans body: xl = h@Wl + bl (fp16) ; xr = h@Wr + br (fp32). bid = node-tile idx.
__device__ __forceinline__ void trans_body(
    int bid, float* s_h, const float* __restrict__ h,
    const float* __restrict__ Wl, const float* __restrict__ bl,
    const float* __restrict__ Wr, const float* __restrict__ br,
    __half* __restrict__ xl, float* __restrict__ xr) {
    int t = threadIdx.x;
    int j = t & 127, hf = t >> 7;
    float wl[kC], wr[kC];
    #pragma unroll
    for (int k = 0; k < kC; ++k) { wl[k] = Wl[k * kHC + j]; wr[k] = Wr[k * kHC + j]; }
    float blj = bl[j], brj = br[j];
    int n0 = bid * 32;
    int nn = min(32, kNodes - n0);
    for (int i = t; i < nn * kC; i += 256) s_h[i] = h[n0 * kC + i];
    __syncthreads();
    int nend = min(nn, hf * 16 + 16);
    for (int n = hf * 16; n < nend; ++n) {
        const float4* h4 = (const float4*)(s_h + n * kC);
        float al = blj, ar = brj;
        #pragma unroll
        for (int kq = 0; kq < 8; ++kq) {
            float4 hv = h4[kq];
            al += hv.x * wl[kq*4] + hv.y * wl[kq*4+1] + hv.z * wl[kq*4+2] + hv.w * wl[kq*4+3];
            ar += hv.x * wr[kq*4] + hv.y * wr[kq*4+1] + hv.z * wr[kq*4+2] + hv.w * wr[kq*4+3];
        }
        long g = (long)(n0 + n) * kHC + j;
        xl[g] = __float2half(al);
        xr[g] = ar;
    }
}

// ---- K_B: role-split fused kernel (layer 0 only).
// blocks [0, kReoGS): reorder, atomic-free, grid-stride 4-deep.
// blocks [kReoGS, +kTransBlocks): trans layer 0 (needs only h).
__global__ void __launch_bounds__(256) k_trans_reorder(
    const float* __restrict__ h,
    const float* __restrict__ Wl, const float* __restrict__ bl,
    const float* __restrict__ Wr, const float* __restrict__ br,
    __half* __restrict__ xl, float* __restrict__ xr,
    const int* __restrict__ src, const int* __restrict__ dst, const float* __restrict__ ea,
    const int* __restrict__ rowptr, const unsigned short* __restrict__ rank,
    int2* __restrict__ epack) {
    __shared__ float s_h[32 * kC];
    if (blockIdx.x < kReoGS) {            // ---- reorder role (starts first)
        const int stride = kReoGS * 256;
        int e = blockIdx.x * 256 + threadIdx.x;
        for (; e + 3 * stride < kNE; e += 4 * stride) {
            int e1 = e + stride, e2 = e + 2 * stride, e3 = e + 3 * stride;
            int d0 = dst[e], d1 = dst[e1], d2 = dst[e2], d3 = dst[e3];
            int r0 = rank[e], r1 = rank[e1], r2 = rank[e2], r3 = rank[e3];
            int p0 = rowptr[d0] + r0, p1 = rowptr[d1] + r1;
            int p2 = rowptr[d2] + r2, p3 = rowptr[d3] + r3;
            epack[p0] = make_int2(src[e],  __float_as_int(ea[e]));
            epack[p1] = make_int2(src[e1], __float_as_int(ea[e1]));
            epack[p2] = make_int2(src[e2], __float_as_int(ea[e2]));
            epack[p3] = make_int2(src[e3], __float_as_int(ea[e3]));
        }
        for (; e < kNE; e += stride) {
            int d = dst[e];
            int pos = rowptr[d] + (int)rank[e];
            epack[pos] = make_int2(src[e], __float_as_int(ea[e]));
        }
        return;
    }
    trans_body(blockIdx.x - kReoGS, s_h, h, Wl, bl, Wr, br, xl, xr);
}

// ---- K_scan: single-block full CSR scan (replaces scan1/2/3).
// 1024 threads x 49 contiguous elems; LDS tree scan of the 1024 partials.
__global__ void __launch_bounds__(1024) k_scan(
    const int* __restrict__ deg, int* __restrict__ rowptr) {
    __shared__ int s[1024];
    const int CH = (kNodes + 1023) / 1024;   // 49
    int t = threadIdx.x;
    int lo = t * CH, hi = min(lo + CH, kNodes);
    int sum = 0;
    for (int i = lo; i < hi; ++i) sum += deg[i];
    s[t] = sum;
    __syncthreads();
    for (int o = 1; o < 1024; o <<= 1) {
        int v = (t >= o) ? s[t - o] : 0;
        __syncthreads();
        s[t] += v;
        __syncthreads();
    }
    int off = (t > 0) ? s[t - 1] : 0;
    for (int i = lo; i < hi; ++i) {
        rowptr[i] = off;
        off += deg[i];
    }
}

// ---- batched edge processing: U pairs (2U edges), loads issued before use.
struct h4 { __half2 a, b; };              // 8 B = 4 halves
template<int U>
__device__ __forceinline__ void gat_batch(
    const int2* __restrict__ epack, int base2, bool slot0, int f,
    const h4* __restrict__ xl4, float4 Wev, float4 xrv, float4 av,
    float& l, float& o0, float& o1, float& o2, float& o3) {
    int2 pa[U], pb[U];
    #pragma unroll
    for (int u = 0; u < U; ++u) {
        pa[u] = epack[base2 + 2 * u];
        pb[u] = epack[base2 + 2 * u + 1];
    }
    h4 xv[U]; float eav[U];
    #pragma unroll
    for (int u = 0; u < U; ++u) {
        int srow = slot0 ? pa[u].x : pb[u].x;
        xv[u] = xl4[(long)srow * 32 + f];
        eav[u] = __int_as_float(slot0 ? pa[u].y : pb[u].y);
    }
    #pragma unroll
    for (int u = 0; u < U; ++u) {
        float2 x01 = __half22float2(xv[u].a), x23 = __half22float2(xv[u].b);
        float a0 = fmaf(eav[u], Wev.x, xrv.x) + x01.x;
        float a1 = fmaf(eav[u], Wev.y, xrv.y) + x01.y;
        float a2 = fmaf(eav[u], Wev.z, xrv.z) + x23.x;
        float a3 = fmaf(eav[u], Wev.w, xrv.w) + x23.y;
        a0 = fmaxf(a0, kSlope * a0); a1 = fmaxf(a1, kSlope * a1);
        a2 = fmaxf(a2, kSlope * a2); a3 = fmaxf(a3, kSlope * a3);
        float pp = red8(a0 * av.x + a1 * av.y + a2 * av.z + a3 * av.w);
        float eu = __builtin_amdgcn_exp2f(pp - kShift2);
        l += eu;
        o0 = fmaf(eu, x01.x, o0); o1 = fmaf(eu, x01.y, o1);
        o2 = fmaf(eu, x23.x, o2); o3 = fmaf(eu, x23.y, o3);
    }
}

// ---- K3: fused edge phase, 4 features/lane, 2 edges/wave, 1 wave/node.
__global__ void __launch_bounds__(256) k_edge(
    const int* __restrict__ rowptr, const int* __restrict__ deg,
    const int2* __restrict__ epack,
    const __half* __restrict__ xl, float* __restrict__ xrg,
    const float* __restrict__ We, const float* __restrict__ att,
    const float* __restrict__ gat_b, float* __restrict__ ps, float* __restrict__ pq) {
    int t = threadIdx.x & 63;
    int w = __builtin_amdgcn_readfirstlane(threadIdx.x >> 6);   // wave 0..3 (uniform)
    int d = blockIdx.x * 4 + w;           // node (50000 = 12500 * 4 exact)
    int f = t & 31;                       // feature quad
    bool slot0 = (t < 32);
    float em0 = slot0 ? 1.f : 0.f;

    const h4* xl4 = (const h4*)xl;        // row stride 32 h4
    long rowq = (long)d * 32;

    float4 xrv = ((const float4*)xrg)[rowq + f];
    float4 Wev = ((const float4*)We)[f];
    float4 av  = ((const float4*)att)[f];
    av.x *= kL2E; av.y *= kL2E; av.z *= kL2E; av.w *= kL2E;
    float4 gb  = ((const float4*)gat_b)[f];

    h4 xs = xl4[rowq + f];
    float2 xs01 = __half22float2(xs.a), xs23 = __half22float2(xs.b);

    // self loop (ea = 0), counted on slot 0 only
    float z0 = xs01.x + xrv.x, z1 = xs01.y + xrv.y;
    float z2 = xs23.x + xrv.z, z3 = xs23.y + xrv.w;
    z0 = fmaxf(z0, kSlope * z0); z1 = fmaxf(z1, kSlope * z1);
    z2 = fmaxf(z2, kSlope * z2); z3 = fmaxf(z3, kSlope * z3);
    float p = red8(z0 * av.x + z1 * av.y + z2 * av.z + z3 * av.w);
    float ee = __builtin_amdgcn_exp2f(p - kShift2) * em0;
    float l = ee;
    float o0 = ee * xs01.x, o1 = ee * xs01.y, o2 = ee * xs23.x, o3 = ee * xs23.y;

    int base = rowptr[d], cnt = deg[d];   // uniform -> SGPR
    int npair = cnt >> 1;
    int e = 0;
    for (; e + 8 <= npair; e += 8)
        gat_batch<8>(epack, base + 2 * e, slot0, f, xl4, Wev, xrv, av, l, o0, o1, o2, o3);
    if (e + 4 <= npair) {
        gat_batch<4>(epack, base + 2 * e, slot0, f, xl4, Wev, xrv, av, l, o0, o1, o2, o3);
        e += 4;
    }
    for (; e < npair; ++e)
        gat_batch<1>(epack, base + 2 * e, slot0, f, xl4, Wev, xrv, av, l, o0, o1, o2, o3);
    if (cnt & 1) {                        // odd tail edge on slot 0 only
        int2 ep = epack[base + cnt - 1];
        int srow = ep.x;
        float eav = __int_as_float(ep.y);
        h4 xv = xl4[(long)srow * 32 + f];
        float2 x01 = __half22float2(xv.a), x23 = __half22float2(xv.b);
        float a0 = fmaf(eav, Wev.x, xrv.x) + x01.x;
        float a1 = fmaf(eav, Wev.y, xrv.y) + x01.y;
        float a2 = fmaf(eav, Wev.z, xrv.z) + x23.x;
        float a3 = fmaf(eav, Wev.w, xrv.w) + x23.y;
        a0 = fmaxf(a0, kSlope * a0); a1 = fmaxf(a1, kSlope * a1);
        a2 = fmaxf(a2, kSlope * a2); a3 = fmaxf(a3, kSlope * a3);
        float pp = red8(a0 * av.x + a1 * av.y + a2 * av.z + a3 * av.w);
        float eu = __builtin_amdgcn_exp2f(pp - kShift2) * em0;
        l += eu;
        o0 = fmaf(eu, x01.x, o0); o1 = fmaf(eu, x01.y, o1);
        o2 = fmaf(eu, x23.x, o2); o3 = fmaf(eu, x23.y, o3);
    }
    // merge the two edge slots
    l  += __shfl_xor(l, 32);
    o0 += __shfl_xor(o0, 32); o1 += __shfl_xor(o1, 32);
    o2 += __shfl_xor(o2, 32); o3 += __shfl_xor(o3, 32);
    float rl = __builtin_amdgcn_rcpf(l);
    float v0 = o0 * rl, v1 = o1 * rl, v2 = o2 * rl, v3 = o3 * rl;
    if (slot0)
        ((float4*)xrg)[rowq + f] = make_float4(v0, v1, v2, v3);  // g overwrites xr
    float vb0 = v0 + gb.x, vb1 = v1 + gb.y, vb2 = v2 + gb.z, vb3 = v3 + gb.w;
    float s = vb0 + vb1 + vb2 + vb3;
    float q = vb0 * vb0 + vb1 * vb1 + vb2 * vb2 + vb3 * vb3;
    #pragma unroll
    for (int mm = 1; mm < 32; mm <<= 1) { s += __shfl_xor(s, mm); q += __shfl_xor(q, mm); }
    if (t == 0) { ps[d] = s; pq[d] = q; }
}

// ---- K4: reduce per-node partials -> stats[2]. 8 blocks + atomic finish
// (stats zeroed once in k_prep; per-layer stats slot).
__global__ void __launch_bounds__(1024) k_statsr(
    const float* __restrict__ ps, const float* __restrict__ pq, float* __restrict__ stats) {
    __shared__ float rs[1024], rq[1024];
    int t = threadIdx.x;
    float s = 0.f, q = 0.f;
    for (int i = blockIdx.x * 1024 + t; i < kNodes; i += 8 * 1024) { s += ps[i]; q += pq[i]; }
    rs[t] = s; rq[t] = q;
    __syncthreads();
    for (int o = 512; o > 0; o >>= 1) {
        if (t < o) { rs[t] += rs[t + o]; rq[t] += rq[t + o]; }
        __syncthreads();
    }
    if (t == 0) { atomicAdd(&stats[0], rs[0]); atomicAdd(&stats[1], rq[0]); }
}

// ---- K5: out = relu(node_ln(relu(graph_ln(g+gat_b)) @ lin_w + lin_b));
// jk_out = max(jk_in, out). If do_trans: also computes next layer's
// xl/xr from out IN-KERNEL (identical f32 math to the old k_trans) —
// kills the standalone trans dispatch and all h round-trips after layer 0.
__global__ void __launch_bounds__(256) k_post(
    const float* __restrict__ g, const float* __restrict__ gat_b,
    const float* __restrict__ ln1w, const float* __restrict__ ln1b,
    const float* __restrict__ linw, const float* __restrict__ linb,
    const float* __restrict__ ln2w, const float* __restrict__ ln2b,
    const float* __restrict__ stats, const float* __restrict__ jk_in,
    float* __restrict__ jk_out, int do_trans,
    const float* __restrict__ Wl, const float* __restrict__ bl,
    const float* __restrict__ Wr, const float* __restrict__ br,
    __half* __restrict__ xl, float* __restrict__ xr) {
    __shared__ float s_lwT[kC * kLWP];    // 16.6 KB, lin_w transposed
    __shared__ float s_vb[8 * kHC];       // 4 KB
    __shared__ float s_hh[8 * kC];        // 1 KB, this block's out-tile
    int t = threadIdx.x;
    int n0 = blockIdx.x * 8;
    int j = t & 127;
    float wl[kC], wr[kC];
    if (do_trans) {                       // issue weight-col loads early
        #pragma unroll
        for (int k = 0; k < kC; ++k) { wl[k] = Wl[k * kHC + j]; wr[k] = Wr[k * kHC + j]; }
    }
    const float inv = 1.f / ((float)kNodes * kHC);
    float mean = stats[0] * inv;
    float var  = stats[1] * inv - mean * mean;
    float rstd = rsqrtf(var + kEps);
    for (int i = t; i < kHC * kC; i += 256) {
        int k = i >> 5, c = i & 31;
        s_lwT[c * kLWP + k] = linw[i];
    }
    for (int i = t; i < 8 * kHC; i += 256) {
        int node = n0 + (i >> 7), f = i & 127;
        float a = (g[(long)node * kHC + f] + gat_b[f] - mean) * rstd * ln1w[f] + ln1b[f];
        s_vb[i] = fmaxf(a, 0.f);
    }
    __syncthreads();
    int n = t >> 5, c = t & 31;
    int node = n0 + n;
    float acc = linb[c];
    const float* vb = s_vb + n * kHC;
    const float* wrt = s_lwT + c * kLWP;
    #pragma unroll 8
    for (int k = 0; k < kHC; k += 4) {
        float4 v4 = *(const float4*)(vb + k);
        float2 w0 = *(const float2*)(wrt + k);
        float2 w1 = *(const float2*)(wrt + k + 2);
        acc += v4.x * w0.x + v4.y * w0.y + v4.z * w1.x + v4.w * w1.y;
    }
    float m = acc;
    #pragma unroll
    for (int mm = 1; mm < 32; mm <<= 1) m += __shfl_xor(m, mm);
    m *= (1.f / kC);
    float dd = acc - m;
    float q = dd * dd;
    #pragma unroll
    for (int mm = 1; mm < 32; mm <<= 1) q += __shfl_xor(q, mm);
    q *= (1.f / kC);
    float out = dd * rsqrtf(q + kEps) * ln2w[c] + ln2b[c];
    out = fmaxf(out, 0.f);
    jk_out[node * kC + c] = fmaxf(jk_in[node * kC + c], out);
    if (!do_trans) return;
    s_hh[n * kC + c] = out;
    __syncthreads();
    // ---- fused trans for the NEXT layer over this block's 8 nodes
    int hf = t >> 7;
    float blj = bl[j], brj = br[j];
    #pragma unroll
    for (int nn2 = 0; nn2 < 4; ++nn2) {
        int nn = hf * 4 + nn2;
        const float4* h4p = (const float4*)(s_hh + nn * kC);
        float al = blj, ar = brj;
        #pragma unroll
        for (int kq = 0; kq < 8; ++kq) {
            float4 hv = h4p[kq];
            al += hv.x * wl[kq*4] + hv.y * wl[kq*4+1] + hv.z * wl[kq*4+2] + hv.w * wl[kq*4+3];
            ar += hv.x * wr[kq*4] + hv.y * wr[kq*4+1] + hv.z * wr[kq*4+2] + hv.w * wr[kq*4+3];
        }
        long gg = (long)(n0 + nn) * kHC + j;
        xl[gg] = __float2half(al);
        xr[gg] = ar;
    }
}

extern "C" void kernel_launch(void* const* d_in, const int* in_sizes, int n_in,
                              void* d_out, int out_size, void* d_ws, size_t ws_size,
                              hipStream_t stream) {
    (void)in_sizes; (void)n_in; (void)out_size; (void)ws_size;
    const float* x     = (const float*)d_in[0];
    const int*   ei    = (const int*)d_in[1];
    const int*   src   = ei;
    const int*   dst   = ei + kNE;
    const float* ea    = (const float*)d_in[2];
    const float* W_emb = (const float*)d_in[3];
    const float* b_emb = (const float*)d_in[4];
    const float* ln0w  = (const float*)d_in[5];
    const float* ln0b  = (const float*)d_in[6];
    const float* Wl    = (const float*)d_in[7];
    const float* bl    = (const float*)d_in[8];
    const float* Wr    = (const float*)d_in[9];
    const float* br    = (const float*)d_in[10];
    const float* We    = (const float*)d_in[11];
    const float* att   = (const float*)d_in[12];
    const float* gat_b = (const float*)d_in[13];
    const float* ln1w  = (const float*)d_in[14];
    const float* ln1b  = (const float*)d_in[15];
    const float* linw  = (const float*)d_in[16];
    const float* linb  = (const float*)d_in[17];
    const float* ln2w  = (const float*)d_in[18];
    const float* ln2b  = (const float*)d_in[19];

    char* wsb = (char*)d_ws;
    float*  h      = (float*)(wsb);                 // 6.4e6 B
    float*  jk     = (float*)(wsb +  6400000);      // 6.4e6 B
    float*  xrg    = (float*)(wsb + 12800000);      // 25.6e6 B (xr, later g)
    __half* xl     = (__half*)(wsb + 38400000);     // 12.8e6 B
    int2*   epack  = (int2*)(wsb + 51200000);       // 6.4e6 B (packed src+ea per edge)
    int*    deg    = (int*)(wsb + 57600000);        // 0.2e6 B
    int*    rowptr = (int*)(wsb + 58000000);        // 0.2e6 B
    float*  stats  = (float*)(wsb + 58201024);      // 16 B (2 layers x 2)
    float*  ps     = (float*)(wsb + 58300000);      // 0.2e6 B
    float*  pq     = (float*)(wsb + 58500000);      // 0.2e6 B
    unsigned short* rank = (unsigned short*)(wsb + 58700000);  // 1.6e6 B
    f16*    Wh     = (f16*)(wsb + 60400000);        // 16 KB (pre-swizzled fp16 W_emb)

    const int edgeBlocks = kNodes / 4;                   // 12500 exact, 4 nodes/block
    const int postBlocks = kNodes / 8;                   // 6250 exact

    // prep: zero deg + stats, convert/swizzle W_emb -> fp16
    hipLaunchKernelGGL(k_prep, dim3(kDegBlocks + 32), dim3(256), 0, stream,
                       (unsigned*)deg, W_emb, Wh, stats);
    hipLaunchKernelGGL(k_embed_hist, dim3(kHistGS + kEmbedBlocks), dim3(256), 0, stream,
                       x, Wh, b_emb, ln0w, ln0b, h, jk, dst, deg, rank);
    hipLaunchKernelGGL(k_scan, dim3(1), dim3(1024), 0, stream, deg, rowptr);
    // fused reorder ∥ trans(layer 0)
    hipLaunchKernelGGL(k_trans_reorder, dim3(kReoGS + kTransBlocks), dim3(256), 0, stream,
                       h, Wl, bl, Wr, br, xl, xrg,
                       src, dst, ea, rowptr, rank, epack);
    for (int l = 0; l < 2; ++l) {
        hipLaunchKernelGGL(k_edge, dim3(edgeBlocks), dim3(256), 0, stream,
                           rowptr, deg, epack, xl, xrg,
                           We + l * kHC, att + l * kH * kC, gat_b + l * kHC, ps, pq);
        hipLaunchKernelGGL(k_statsr, dim3(8), dim3(1024), 0, stream, ps, pq, stats + 2 * l);
        // post: l=0 fuses next layer's trans (writes xl/xr); l=1 writes d_out
        hipLaunchKernelGGL(k_post, dim3(postBlocks), dim3(256), 0, stream,
                           xrg, gat_b + l * kHC, ln1w + l * kHC, ln1b + l * kHC,
                           linw + l * kHC * kC, linb + l * kC,
                           ln2w + l * kC, ln2b + l * kC, stats + 2 * l, jk,
                           (l == 1) ? (float*)d_out : jk,
                           (l == 0) ? 1 : 0,
                           Wl + kC * kHC, bl + kHC, Wr + kC * kHC, br + kHC,
                           xl, xrg);
    }
}

// Round 12
// 422.677 us; speedup vs baseline: 1.1482x; 1.1482x over previous
//
#include <hip/hip_runtime.h>
#include <hip/hip_fp16.h>

constexpr int kNodes = 50000;
constexpr int kNE    = 800000;            // edges before self loops
constexpr int kFin   = 256;
constexpr int kC     = 32;
constexpr int kH     = 4;
constexpr int kHC    = 128;               // kH * kC
constexpr int kTN    = 16;                // nodes per k_embed block
constexpr int kLWP   = 130;               // padded s_lwT row in k_post (float2-aligned, 2-way alias)
constexpr int kEmbedBlocks = kNodes / kTN;        // 3125
constexpr int kTransBlocks = (kNodes + 31) / 32;  // 1563
constexpr int kHistGS = 256;              // grid-stride hist blocks (4-deep atomic MLP)
constexpr int kReoGS  = 256;              // grid-stride reorder blocks
constexpr int kDegBlocks = (kNodes + 255) / 256;  // 196 (k_prep deg-zero role)
constexpr float kEps   = 1e-5f;
constexpr float kSlope = 0.2f;
constexpr float kL2E   = 1.44269504f;     // log2(e): fold into att so exp is 1 instr
constexpr float kShift2 = 8.0f * 1.44269504f; // softmax-invariant shift (exp2 domain)

typedef _Float16 f16;
typedef _Float16 f16x2 __attribute__((ext_vector_type(2)));
struct alignas(16) h8 { f16x2 v[4]; };    // 8 halves = 16 B

__device__ __forceinline__ float fdot2_(f16x2 a, f16x2 b, float c) {
#if __has_builtin(__builtin_amdgcn_fdot2)
    return __builtin_amdgcn_fdot2(a, b, c, false);
#else
    return fmaf((float)a.x, (float)b.x, fmaf((float)a.y, (float)b.y, c));
#endif
}

// ---- DPP butterfly add: v += partner(v), pure VALU (no DS pipe).
template<int CTRL>
__device__ __forceinline__ float dpp_add(float v) {
    int x = __builtin_amdgcn_update_dpp(0, __float_as_int(v), CTRL, 0xF, 0xF, true);
    return v + __int_as_float(x);
}
// 8-lane sum (head = 8 lanes x 4 features): xor1, xor2, then row_half_mirror.
__device__ __forceinline__ float red8(float p) {
    p = dpp_add<0xB1>(p);
    p = dpp_add<0x4E>(p);
    p = dpp_add<0x141>(p);
    return p;
}

// ---- K0: prep — zero deg (196 blocks) + convert W to fp16 PRE-SWIZZLED
// [i8][c][8] (32 blocks) + zero both layers' stats.
__global__ void __launch_bounds__(256) k_prep(
    unsigned* __restrict__ deg, const float* __restrict__ W, f16* __restrict__ Wh,
    float* __restrict__ stats) {
    int t = threadIdx.x;
    if (blockIdx.x == 0 && t < 4) stats[t] = 0.f;
    if (blockIdx.x < kDegBlocks) {
        int i = blockIdx.x * 256 + t;
        if (i < kNodes) deg[i] = 0u;
        return;
    }
    int i = (blockIdx.x - kDegBlocks) * 256 + t;   // 32 blocks x 256 = 8192 = kFin*kC
    int k = i >> 5, c = i & 31;
    Wh[((k >> 3) * kC + c) * 8 + (k & 7)] = (f16)W[i];
}

// ---- K_A: role-split fused kernel, fp16 operands + v_dot2_f32_f16.
// blocks [0, kHistGS): grid-stride degree histogram, 4-deep batches; the
// atomicAdd RETURN VALUE is the edge's rank within its dst row -> rank[e].
// blocks [kHistGS, +kEmbedBlocks): h0 = relu(node_ln(x @ W_emb + b_emb)); jk = h0.
__global__ void __launch_bounds__(256) k_embed_hist(
    const float* __restrict__ x, const f16* __restrict__ Wh, const float* __restrict__ b,
    const float* __restrict__ lnw, const float* __restrict__ lnb,
    float* __restrict__ h, float* __restrict__ jk,
    const int* __restrict__ dst, int* __restrict__ deg, unsigned short* __restrict__ rank) {
    __shared__ f16 sxh[kTN * kFin];       // 8 KB
    __shared__ f16 sWh[kFin / 8 * kC * 8];// 16 KB, [i8][c] blocks of 8 halves
    int t = threadIdx.x;
    if (blockIdx.x < kHistGS) {           // ---- hist role (grid-stride, 4-deep)
        const int stride = kHistGS * 256;
        int e = blockIdx.x * 256 + t;
        for (; e + 3 * stride < kNE; e += 4 * stride) {
            int d0 = dst[e], d1 = dst[e + stride], d2 = dst[e + 2 * stride], d3 = dst[e + 3 * stride];
            int r0 = atomicAdd(&deg[d0], 1);
            int r1 = atomicAdd(&deg[d1], 1);
            int r2 = atomicAdd(&deg[d2], 1);
            int r3 = atomicAdd(&deg[d3], 1);
            rank[e] = (unsigned short)r0;
            rank[e + stride] = (unsigned short)r1;
            rank[e + 2 * stride] = (unsigned short)r2;
            rank[e + 3 * stride] = (unsigned short)r3;
        }
        for (; e < kNE; e += stride) {
            int d = dst[e];
            rank[e] = (unsigned short)atomicAdd(&deg[d], 1);
        }
        return;
    }
    // ---- embed role
    int n0 = (blockIdx.x - kHistGS) * kTN;       // 50000 = 3125 * 16 exact
    {
        const h8* Wg = (const h8*)Wh;
        h8* sW8 = (h8*)sWh;
        for (int i = t; i < kFin * kC / 8; i += 256) sW8[i] = Wg[i];
    }
    const float2* xg2 = (const float2*)(x + (long)n0 * kFin);
    f16x2* sx2 = (f16x2*)sxh;
    for (int i = t; i < kTN * kFin / 2; i += 256) {
        float2 v = xg2[i];
        f16x2 hv; hv.x = (f16)v.x; hv.y = (f16)v.y;
        sx2[i] = hv;
    }
    __syncthreads();
    int c = t & 31, n2 = t >> 5;          // n2 = 0..7
    const h8* xa = (const h8*)(sxh + n2 * kFin);
    const h8* xb = (const h8*)(sxh + (n2 + 8) * kFin);
    const h8* wr = (const h8*)sWh;        // [i8*kC + c]
    float a0 = 0.f, a0b = 0.f, a1 = 0.f, a1b = 0.f;
    #pragma unroll 8
    for (int i8 = 0; i8 < kFin / 8; ++i8) {
        h8 xv0 = xa[i8];
        h8 xv1 = xb[i8];
        h8 wv  = wr[i8 * kC + c];
        a0  = fdot2_(xv0.v[0], wv.v[0], a0);
        a0b = fdot2_(xv0.v[1], wv.v[1], a0b);
        a0  = fdot2_(xv0.v[2], wv.v[2], a0);
        a0b = fdot2_(xv0.v[3], wv.v[3], a0b);
        a1  = fdot2_(xv1.v[0], wv.v[0], a1);
        a1b = fdot2_(xv1.v[1], wv.v[1], a1b);
        a1  = fdot2_(xv1.v[2], wv.v[2], a1);
        a1b = fdot2_(xv1.v[3], wv.v[3], a1b);
    }
    float acc0 = a0 + a0b, acc1 = a1 + a1b;
    float bc = b[c], lw = lnw[c], lb = lnb[c];
    {
        float y = acc0 + bc;
        float m = y;
        #pragma unroll
        for (int o = 1; o < 32; o <<= 1) m += __shfl_xor(m, o);
        m *= (1.f / kC);
        float xc = y - m, v = xc * xc;
        #pragma unroll
        for (int o = 1; o < 32; o <<= 1) v += __shfl_xor(v, o);
        v *= (1.f / kC);
        float out = fmaxf(xc * rsqrtf(v + kEps) * lw + lb, 0.f);
        int node = n0 + n2;
        h[node * kC + c] = out;
        jk[node * kC + c] = out;
    }
    {
        float y = acc1 + bc;
        float m = y;
        #pragma unroll
        for (int o = 1; o < 32; o <<= 1) m += __shfl_xor(m, o);
        m *= (1.f / kC);
        float xc = y - m, v = xc * xc;
        #pragma unroll
        for (int o = 1; o < 32; o <<= 1) v += __shfl_xor(v, o);
        v *= (1.f / kC);
        float out = fmaxf(xc * rsqrtf(v + kEps) * lw + lb, 0.f);
        int node = n0 + n2 + 8;
        h[node * kC + c] = out;
        jk[node * kC + c] = out;
    }
}

// ---- trans body: xl = h@Wl + bl (fp16) ; xr = h@Wr + br (fp32). bid = node-tile idx.
__device__ __forceinline__ void trans_body(
    int bid, float* s_h, const float* __restrict__ h,
    const float* __restrict__ Wl, const float* __restrict__ bl,
    const float* __restrict__ Wr, const float* __restrict__ br,
    __half* __restrict__ xl, float* __restrict__ xr) {
    int t = threadIdx.x;
    int j = t & 127, hf = t >> 7;
    float wl[kC], wr[kC];
    #pragma unroll
    for (int k = 0; k < kC; ++k) { wl[k] = Wl[k * kHC + j]; wr[k] = Wr[k * kHC + j]; }
    float blj = bl[j], brj = br[j];
    int n0 = bid * 32;
    int nn = min(32, kNodes - n0);
    for (int i = t; i < nn * kC; i += 256) s_h[i] = h[n0 * kC + i];
    __syncthreads();
    int nend = min(nn, hf * 16 + 16);
    for (int n = hf * 16; n < nend; ++n) {
        const float4* h4 = (const float4*)(s_h + n * kC);
        float al = blj, ar = brj;
        #pragma unroll
        for (int kq = 0; kq < 8; ++kq) {
            float4 hv = h4[kq];
            al += hv.x * wl[kq*4] + hv.y * wl[kq*4+1] + hv.z * wl[kq*4+2] + hv.w * wl[kq*4+3];
            ar += hv.x * wr[kq*4] + hv.y * wr[kq*4+1] + hv.z * wr[kq*4+2] + hv.w * wr[kq*4+3];
        }
        long g = (long)(n0 + n) * kHC + j;
        xl[g] = __float2half(al);
        xr[g] = ar;
    }
}

// ---- K_B: role-split fused kernel (layer 0 only).
// blocks [0, kReoGS): reorder, atomic-free, grid-stride 4-deep.
// blocks [kReoGS, +kTransBlocks): trans layer 0 (needs only h).
__global__ void __launch_bounds__(256) k_trans_reorder(
    const float* __restrict__ h,
    const float* __restrict__ Wl, const float* __restrict__ bl,
    const float* __restrict__ Wr, const float* __restrict__ br,
    __half* __restrict__ xl, float* __restrict__ xr,
    const int* __restrict__ src, const int* __restrict__ dst, const float* __restrict__ ea,
    const int* __restrict__ rowptr, const unsigned short* __restrict__ rank,
    int2* __restrict__ epack) {
    __shared__ float s_h[32 * kC];
    if (blockIdx.x < kReoGS) {            // ---- reorder role (starts first)
        const int stride = kReoGS * 256;
        int e = blockIdx.x * 256 + threadIdx.x;
        for (; e + 3 * stride < kNE; e += 4 * stride) {
            int e1 = e + stride, e2 = e + 2 * stride, e3 = e + 3 * stride;
            int d0 = dst[e], d1 = dst[e1], d2 = dst[e2], d3 = dst[e3];
            int r0 = rank[e], r1 = rank[e1], r2 = rank[e2], r3 = rank[e3];
            int p0 = rowptr[d0] + r0, p1 = rowptr[d1] + r1;
            int p2 = rowptr[d2] + r2, p3 = rowptr[d3] + r3;
            epack[p0] = make_int2(src[e],  __float_as_int(ea[e]));
            epack[p1] = make_int2(src[e1], __float_as_int(ea[e1]));
            epack[p2] = make_int2(src[e2], __float_as_int(ea[e2]));
            epack[p3] = make_int2(src[e3], __float_as_int(ea[e3]));
        }
        for (; e < kNE; e += stride) {
            int d = dst[e];
            int pos = rowptr[d] + (int)rank[e];
            epack[pos] = make_int2(src[e], __float_as_int(ea[e]));
        }
        return;
    }
    trans_body(blockIdx.x - kReoGS, s_h, h, Wl, bl, Wr, br, xl, xr);
}

// ---- CSR scans (parallel 3-dispatch version; single-block scan was 76 µs —
// one CU has no MLP to hide 50k load round-trips. Dispatch overhead << that.)
__global__ void __launch_bounds__(256) k_scan1(const int* __restrict__ deg,
                                               int* __restrict__ excl, int* __restrict__ bsum) {
    __shared__ int s[256];
    int t = threadIdx.x;
    int i = blockIdx.x * 256 + t;
    int v = (i < kNodes) ? deg[i] : 0;
    s[t] = v;
    __syncthreads();
    for (int o = 1; o < 256; o <<= 1) {
        int tv = (t >= o) ? s[t - o] : 0;
        __syncthreads();
        s[t] += tv;
        __syncthreads();
    }
    if (i < kNodes) excl[i] = s[t] - v;
    if (t == 255) bsum[blockIdx.x] = s[255];
}

__global__ void __launch_bounds__(256) k_scan2(int* __restrict__ bsum, int nb) {
    __shared__ int s[256];
    int t = threadIdx.x;
    int v = (t < nb) ? bsum[t] : 0;
    s[t] = v;
    __syncthreads();
    for (int o = 1; o < 256; o <<= 1) {
        int tv = (t >= o) ? s[t - o] : 0;
        __syncthreads();
        s[t] += tv;
        __syncthreads();
    }
    if (t < nb) bsum[t] = s[t];
}

__global__ void __launch_bounds__(256) k_scan3(int* __restrict__ excl, const int* __restrict__ bsum) {
    int i = blockIdx.x * 256 + threadIdx.x;
    if (i >= kNodes) return;
    if (blockIdx.x > 0) excl[i] += bsum[blockIdx.x - 1];
}

// ---- batched edge processing: U pairs (2U edges), loads issued before use.
struct h4 { __half2 a, b; };              // 8 B = 4 halves
template<int U>
__device__ __forceinline__ void gat_batch(
    const int2* __restrict__ epack, int base2, bool slot0, int f,
    const h4* __restrict__ xl4, float4 Wev, float4 xrv, float4 av,
    float& l, float& o0, float& o1, float& o2, float& o3) {
    int2 pa[U], pb[U];
    #pragma unroll
    for (int u = 0; u < U; ++u) {
        pa[u] = epack[base2 + 2 * u];
        pb[u] = epack[base2 + 2 * u + 1];
    }
    h4 xv[U]; float eav[U];
    #pragma unroll
    for (int u = 0; u < U; ++u) {
        int srow = slot0 ? pa[u].x : pb[u].x;
        xv[u] = xl4[(long)srow * 32 + f];
        eav[u] = __int_as_float(slot0 ? pa[u].y : pb[u].y);
    }
    #pragma unroll
    for (int u = 0; u < U; ++u) {
        float2 x01 = __half22float2(xv[u].a), x23 = __half22float2(xv[u].b);
        float a0 = fmaf(eav[u], Wev.x, xrv.x) + x01.x;
        float a1 = fmaf(eav[u], Wev.y, xrv.y) + x01.y;
        float a2 = fmaf(eav[u], Wev.z, xrv.z) + x23.x;
        float a3 = fmaf(eav[u], Wev.w, xrv.w) + x23.y;
        a0 = fmaxf(a0, kSlope * a0); a1 = fmaxf(a1, kSlope * a1);
        a2 = fmaxf(a2, kSlope * a2); a3 = fmaxf(a3, kSlope * a3);
        float pp = red8(a0 * av.x + a1 * av.y + a2 * av.z + a3 * av.w);
        float eu = __builtin_amdgcn_exp2f(pp - kShift2);
        l += eu;
        o0 = fmaf(eu, x01.x, o0); o1 = fmaf(eu, x01.y, o1);
        o2 = fmaf(eu, x23.x, o2); o3 = fmaf(eu, x23.y, o3);
    }
}

// ---- K3: fused edge phase, 4 features/lane, 2 edges/wave, 1 wave/node.
__global__ void __launch_bounds__(256) k_edge(
    const int* __restrict__ rowptr, const int* __restrict__ deg,
    const int2* __restrict__ epack,
    const __half* __restrict__ xl, float* __restrict__ xrg,
    const float* __restrict__ We, const float* __restrict__ att,
    const float* __restrict__ gat_b, float* __restrict__ ps, float* __restrict__ pq) {
    int t = threadIdx.x & 63;
    int w = __builtin_amdgcn_readfirstlane(threadIdx.x >> 6);   // wave 0..3 (uniform)
    int d = blockIdx.x * 4 + w;           // node (50000 = 12500 * 4 exact)
    int f = t & 31;                       // feature quad
    bool slot0 = (t < 32);
    float em0 = slot0 ? 1.f : 0.f;

    const h4* xl4 = (const h4*)xl;        // row stride 32 h4
    long rowq = (long)d * 32;

    float4 xrv = ((const float4*)xrg)[rowq + f];
    float4 Wev = ((const float4*)We)[f];
    float4 av  = ((const float4*)att)[f];
    av.x *= kL2E; av.y *= kL2E; av.z *= kL2E; av.w *= kL2E;
    float4 gb  = ((const float4*)gat_b)[f];

    h4 xs = xl4[rowq + f];
    float2 xs01 = __half22float2(xs.a), xs23 = __half22float2(xs.b);

    // self loop (ea = 0), counted on slot 0 only
    float z0 = xs01.x + xrv.x, z1 = xs01.y + xrv.y;
    float z2 = xs23.x + xrv.z, z3 = xs23.y + xrv.w;
    z0 = fmaxf(z0, kSlope * z0); z1 = fmaxf(z1, kSlope * z1);
    z2 = fmaxf(z2, kSlope * z2); z3 = fmaxf(z3, kSlope * z3);
    float p = red8(z0 * av.x + z1 * av.y + z2 * av.z + z3 * av.w);
    float ee = __builtin_amdgcn_exp2f(p - kShift2) * em0;
    float l = ee;
    float o0 = ee * xs01.x, o1 = ee * xs01.y, o2 = ee * xs23.x, o3 = ee * xs23.y;

    int base = rowptr[d], cnt = deg[d];   // uniform -> SGPR
    int npair = cnt >> 1;
    int e = 0;
    for (; e + 8 <= npair; e += 8)
        gat_batch<8>(epack, base + 2 * e, slot0, f, xl4, Wev, xrv, av, l, o0, o1, o2, o3);
    if (e + 4 <= npair) {
        gat_batch<4>(epack, base + 2 * e, slot0, f, xl4, Wev, xrv, av, l, o0, o1, o2, o3);
        e += 4;
    }
    for (; e < npair; ++e)
        gat_batch<1>(epack, base + 2 * e, slot0, f, xl4, Wev, xrv, av, l, o0, o1, o2, o3);
    if (cnt & 1) {                        // odd tail edge on slot 0 only
        int2 ep = epack[base + cnt - 1];
        int srow = ep.x;
        float eav = __int_as_float(ep.y);
        h4 xv = xl4[(long)srow * 32 + f];
        float2 x01 = __half22float2(xv.a), x23 = __half22float2(xv.b);
        float a0 = fmaf(eav, Wev.x, xrv.x) + x01.x;
        float a1 = fmaf(eav, Wev.y, xrv.y) + x01.y;
        float a2 = fmaf(eav, Wev.z, xrv.z) + x23.x;
        float a3 = fmaf(eav, Wev.w, xrv.w) + x23.y;
        a0 = fmaxf(a0, kSlope * a0); a1 = fmaxf(a1, kSlope * a1);
        a2 = fmaxf(a2, kSlope * a2); a3 = fmaxf(a3, kSlope * a3);
        float pp = red8(a0 * av.x + a1 * av.y + a2 * av.z + a3 * av.w);
        float eu = __builtin_amdgcn_exp2f(pp - kShift2) * em0;
        l += eu;
        o0 = fmaf(eu, x01.x, o0); o1 = fmaf(eu, x01.y, o1);
        o2 = fmaf(eu, x23.x, o2); o3 = fmaf(eu, x23.y, o3);
    }
    // merge the two edge slots
    l  += __shfl_xor(l, 32);
    o0 += __shfl_xor(o0, 32); o1 += __shfl_xor(o1, 32);
    o2 += __shfl_xor(o2, 32); o3 += __shfl_xor(o3, 32);
    float rl = __builtin_amdgcn_rcpf(l);
    float v0 = o0 * rl, v1 = o1 * rl, v2 = o2 * rl, v3 = o3 * rl;
    if (slot0)
        ((float4*)xrg)[rowq + f] = make_float4(v0, v1, v2, v3);  // g overwrites xr
    float vb0 = v0 + gb.x, vb1 = v1 + gb.y, vb2 = v2 + gb.z, vb3 = v3 + gb.w;
    float s = vb0 + vb1 + vb2 + vb3;
    float q = vb0 * vb0 + vb1 * vb1 + vb2 * vb2 + vb3 * vb3;
    #pragma unroll
    for (int mm = 1; mm < 32; mm <<= 1) { s += __shfl_xor(s, mm); q += __shfl_xor(q, mm); }
    if (t == 0) { ps[d] = s; pq[d] = q; }
}

// ---- K4: reduce per-node partials -> stats[2]. 8 blocks + atomic finish
// (stats zeroed once in k_prep; per-layer stats slot).
__global__ void __launch_bounds__(1024) k_statsr(
    const float* __restrict__ ps, const float* __restrict__ pq, float* __restrict__ stats) {
    __shared__ float rs[1024], rq[1024];
    int t = threadIdx.x;
    float s = 0.f, q = 0.f;
    for (int i = blockIdx.x * 1024 + t; i < kNodes; i += 8 * 1024) { s += ps[i]; q += pq[i]; }
    rs[t] = s; rq[t] = q;
    __syncthreads();
    for (int o = 512; o > 0; o >>= 1) {
        if (t < o) { rs[t] += rs[t + o]; rq[t] += rq[t + o]; }
        __syncthreads();
    }
    if (t == 0) { atomicAdd(&stats[0], rs[0]); atomicAdd(&stats[1], rq[0]); }
}

// ---- K5: out = relu(node_ln(relu(graph_ln(g+gat_b)) @ lin_w + lin_b));
// jk_out = max(jk_in, out). If do_trans: also computes next layer's
// xl/xr from out IN-KERNEL (identical f32 math to the old k_trans).
__global__ void __launch_bounds__(256) k_post(
    const float* __restrict__ g, const float* __restrict__ gat_b,
    const float* __restrict__ ln1w, const float* __restrict__ ln1b,
    const float* __restrict__ linw, const float* __restrict__ linb,
    const float* __restrict__ ln2w, const float* __restrict__ ln2b,
    const float* __restrict__ stats, const float* __restrict__ jk_in,
    float* __restrict__ jk_out, int do_trans,
    const float* __restrict__ Wl, const float* __restrict__ bl,
    const float* __restrict__ Wr, const float* __restrict__ br,
    __half* __restrict__ xl, float* __restrict__ xr) {
    __shared__ float s_lwT[kC * kLWP];    // 16.6 KB, lin_w transposed
    __shared__ float s_vb[8 * kHC];       // 4 KB
    __shared__ float s_hh[8 * kC];        // 1 KB, this block's out-tile
    int t = threadIdx.x;
    int n0 = blockIdx.x * 8;
    int j = t & 127;
    float wl[kC], wr[kC];
    if (do_trans) {                       // issue weight-col loads early
        #pragma unroll
        for (int k = 0; k < kC; ++k) { wl[k] = Wl[k * kHC + j]; wr[k] = Wr[k * kHC + j]; }
    }
    const float inv = 1.f / ((float)kNodes * kHC);
    float mean = stats[0] * inv;
    float var  = stats[1] * inv - mean * mean;
    float rstd = rsqrtf(var + kEps);
    for (int i = t; i < kHC * kC; i += 256) {
        int k = i >> 5, c = i & 31;
        s_lwT[c * kLWP + k] = linw[i];
    }
    for (int i = t; i < 8 * kHC; i += 256) {
        int node = n0 + (i >> 7), f = i & 127;
        float a = (g[(long)node * kHC + f] + gat_b[f] - mean) * rstd * ln1w[f] + ln1b[f];
        s_vb[i] = fmaxf(a, 0.f);
    }
    __syncthreads();
    int n = t >> 5, c = t & 31;
    int node = n0 + n;
    float acc = linb[c];
    const float* vb = s_vb + n * kHC;
    const float* wrt = s_lwT + c * kLWP;
    #pragma unroll 8
    for (int k = 0; k < kHC; k += 4) {
        float4 v4 = *(const float4*)(vb + k);
        float2 w0 = *(const float2*)(wrt + k);
        float2 w1 = *(const float2*)(wrt + k + 2);
        acc += v4.x * w0.x + v4.y * w0.y + v4.z * w1.x + v4.w * w1.y;
    }
    float m = acc;
    #pragma unroll
    for (int mm = 1; mm < 32; mm <<= 1) m += __shfl_xor(m, mm);
    m *= (1.f / kC);
    float dd = acc - m;
    float q = dd * dd;
    #pragma unroll
    for (int mm = 1; mm < 32; mm <<= 1) q += __shfl_xor(q, mm);
    q *= (1.f / kC);
    float out = dd * rsqrtf(q + kEps) * ln2w[c] + ln2b[c];
    out = fmaxf(out, 0.f);
    jk_out[node * kC + c] = fmaxf(jk_in[node * kC + c], out);
    if (!do_trans) return;
    s_hh[n * kC + c] = out;
    __syncthreads();
    // ---- fused trans for the NEXT layer over this block's 8 nodes
    int hf = t >> 7;
    float blj = bl[j], brj = br[j];
    #pragma unroll
    for (int nn2 = 0; nn2 < 4; ++nn2) {
        int nn = hf * 4 + nn2;
        const float4* h4p = (const float4*)(s_hh + nn * kC);
        float al = blj, ar = brj;
        #pragma unroll
        for (int kq = 0; kq < 8; ++kq) {
            float4 hv = h4p[kq];
            al += hv.x * wl[kq*4] + hv.y * wl[kq*4+1] + hv.z * wl[kq*4+2] + hv.w * wl[kq*4+3];
            ar += hv.x * wr[kq*4] + hv.y * wr[kq*4+1] + hv.z * wr[kq*4+2] + hv.w * wr[kq*4+3];
        }
        long gg = (long)(n0 + nn) * kHC + j;
        xl[gg] = __float2half(al);
        xr[gg] = ar;
    }
}

extern "C" void kernel_launch(void* const* d_in, const int* in_sizes, int n_in,
                              void* d_out, int out_size, void* d_ws, size_t ws_size,
                              hipStream_t stream) {
    (void)in_sizes; (void)n_in; (void)out_size; (void)ws_size;
    const float* x     = (const float*)d_in[0];
    const int*   ei    = (const int*)d_in[1];
    const int*   src   = ei;
    const int*   dst   = ei + kNE;
    const float* ea    = (const float*)d_in[2];
    const float* W_emb = (const float*)d_in[3];
    const float* b_emb = (const float*)d_in[4];
    const float* ln0w  = (const float*)d_in[5];
    const float* ln0b  = (const float*)d_in[6];
    const float* Wl    = (const float*)d_in[7];
    const float* bl    = (const float*)d_in[8];
    const float* Wr    = (const float*)d_in[9];
    const float* br    = (const float*)d_in[10];
    const float* We    = (const float*)d_in[11];
    const float* att   = (const float*)d_in[12];
    const float* gat_b = (const float*)d_in[13];
    const float* ln1w  = (const float*)d_in[14];
    const float* ln1b  = (const float*)d_in[15];
    const float* linw  = (const float*)d_in[16];
    const float* linb  = (const float*)d_in[17];
    const float* ln2w  = (const float*)d_in[18];
    const float* ln2b  = (const float*)d_in[19];

    char* wsb = (char*)d_ws;
    float*  h      = (float*)(wsb);                 // 6.4e6 B
    float*  jk     = (float*)(wsb +  6400000);      // 6.4e6 B
    float*  xrg    = (float*)(wsb + 12800000);      // 25.6e6 B (xr, later g)
    __half* xl     = (__half*)(wsb + 38400000);     // 12.8e6 B
    int2*   epack  = (int2*)(wsb + 51200000);       // 6.4e6 B (packed src+ea per edge)
    int*    deg    = (int*)(wsb + 57600000);        // 0.2e6 B
    int*    rowptr = (int*)(wsb + 58000000);        // 0.2e6 B
    int*    bsum   = (int*)(wsb + 58200000);        // 1 KB
    float*  stats  = (float*)(wsb + 58201024);      // 16 B (2 layers x 2)
    float*  ps     = (float*)(wsb + 58300000);      // 0.2e6 B
    float*  pq     = (float*)(wsb + 58500000);      // 0.2e6 B
    unsigned short* rank = (unsigned short*)(wsb + 58700000);  // 1.6e6 B
    f16*    Wh     = (f16*)(wsb + 60400000);        // 16 KB (pre-swizzled fp16 W_emb)

    const int scanBlocks = (kNodes + 255) / 256;         // 196
    const int edgeBlocks = kNodes / 4;                   // 12500 exact, 4 nodes/block
    const int postBlocks = kNodes / 8;                   // 6250 exact

    // prep: zero deg + stats, convert/swizzle W_emb -> fp16
    hipLaunchKernelGGL(k_prep, dim3(kDegBlocks + 32), dim3(256), 0, stream,
                       (unsigned*)deg, W_emb, Wh, stats);
    hipLaunchKernelGGL(k_embed_hist, dim3(kHistGS + kEmbedBlocks), dim3(256), 0, stream,
                       x, Wh, b_emb, ln0w, ln0b, h, jk, dst, deg, rank);
    hipLaunchKernelGGL(k_scan1, dim3(scanBlocks), dim3(256), 0, stream, deg, rowptr, bsum);
    hipLaunchKernelGGL(k_scan2, dim3(1), dim3(256), 0, stream, bsum, scanBlocks);
    hipLaunchKernelGGL(k_scan3, dim3(scanBlocks), dim3(256), 0, stream, rowptr, bsum);
    // fused reorder ∥ trans(layer 0)
    hipLaunchKernelGGL(k_trans_reorder, dim3(kReoGS + kTransBlocks), dim3(256), 0, stream,
                       h, Wl, bl, Wr, br, xl, xrg,
                       src, dst, ea, rowptr, rank, epack);
    for (int l = 0; l < 2; ++l) {
        hipLaunchKernelGGL(k_edge, dim3(edgeBlocks), dim3(256), 0, stream,
                           rowptr, deg, epack, xl, xrg,
                           We + l * kHC, att + l * kH * kC, gat_b + l * kHC, ps, pq);
        hipLaunchKernelGGL(k_statsr, dim3(8), dim3(1024), 0, stream, ps, pq, stats + 2 * l);
        // post: l=0 fuses next layer's trans (writes xl/xr); l=1 writes d_out
        hipLaunchKernelGGL(k_post, dim3(postBlocks), dim3(256), 0, stream,
                           xrg, gat_b + l * kHC, ln1w + l * kHC, ln1b + l * kHC,
                           linw + l * kHC * kC, linb + l * kC,
                           ln2w + l * kC, ln2b + l * kC, stats + 2 * l, jk,
                           (l == 1) ? (float*)d_out : jk,
                           (l == 0) ? 1 : 0,
                           Wl + kC * kHC, bl + kHC, Wr + kC * kHC, br + kHC,
                           xl, xrg);
    }
}

// Round 13
// 414.066 us; speedup vs baseline: 1.1721x; 1.0208x over previous
//
#include <hip/hip_runtime.h>
#include <hip/hip_fp16.h>

constexpr int kNodes = 50000;
constexpr int kNE    = 800000;            // edges before self loops
constexpr int kFin   = 256;
constexpr int kC     = 32;
constexpr int kH     = 4;
constexpr int kHC    = 128;               // kH * kC
constexpr int kTN    = 16;                // nodes per k_embed block
constexpr int kLWP   = 130;               // padded s_lwT row in k_post (float2-aligned, 2-way alias)
constexpr int kEmbedBlocks = kNodes / kTN;        // 3125
constexpr int kTransBlocks = (kNodes + 31) / 32;  // 1563
constexpr int kHistGS = 256;              // grid-stride hist blocks (4-deep atomic MLP)
constexpr int kReoGS  = 256;              // grid-stride reorder blocks
constexpr int kDegBlocks = (kNodes + 255) / 256;  // 196 (k_prep deg-zero role)
constexpr float kEps   = 1e-5f;
constexpr float kSlope = 0.2f;
constexpr float kL2E   = 1.44269504f;     // log2(e): fold into att so exp is 1 instr
constexpr float kShift2 = 8.0f * 1.44269504f; // softmax-invariant shift (exp2 domain)

typedef _Float16 f16;
typedef _Float16 f16x2 __attribute__((ext_vector_type(2)));
typedef _Float16 f16x4 __attribute__((ext_vector_type(4)));
struct alignas(16) h8 { f16x2 v[4]; };    // 8 halves = 16 B

__device__ __forceinline__ float fdot2_(f16x2 a, f16x2 b, float c) {
#if __has_builtin(__builtin_amdgcn_fdot2)
    return __builtin_amdgcn_fdot2(a, b, c, false);
#else
    return fmaf((float)a.x, (float)b.x, fmaf((float)a.y, (float)b.y, c));
#endif
}

// ---- DPP butterfly add: v += partner(v), pure VALU (no DS pipe).
template<int CTRL>
__device__ __forceinline__ float dpp_add(float v) {
    int x = __builtin_amdgcn_update_dpp(0, __float_as_int(v), CTRL, 0xF, 0xF, true);
    return v + __int_as_float(x);
}
// 8-lane sum (head = 8 lanes x 4 features): xor1, xor2, then row_half_mirror.
__device__ __forceinline__ float red8(float p) {
    p = dpp_add<0xB1>(p);
    p = dpp_add<0x4E>(p);
    p = dpp_add<0x141>(p);
    return p;
}

// ---- K0: prep — zero deg (196 blocks) + convert W to fp16 PRE-SWIZZLED
// [i8][c][8] (32 blocks) + zero both layers' stats.
__global__ void __launch_bounds__(256) k_prep(
    unsigned* __restrict__ deg, const float* __restrict__ W, f16* __restrict__ Wh,
    float* __restrict__ stats) {
    int t = threadIdx.x;
    if (blockIdx.x == 0 && t < 4) stats[t] = 0.f;
    if (blockIdx.x < kDegBlocks) {
        int i = blockIdx.x * 256 + t;
        if (i < kNodes) deg[i] = 0u;
        return;
    }
    int i = (blockIdx.x - kDegBlocks) * 256 + t;   // 32 blocks x 256 = 8192 = kFin*kC
    int k = i >> 5, c = i & 31;
    Wh[((k >> 3) * kC + c) * 8 + (k & 7)] = (f16)W[i];
}

// ---- K_A: role-split fused kernel, fp16 operands + v_dot2_f32_f16.
// blocks [0, kHistGS): grid-stride degree histogram, 4-deep batches; the
// atomicAdd RETURN VALUE is the edge's rank within its dst row -> rank[e].
// blocks [kHistGS, +kEmbedBlocks): h0 = relu(node_ln(x @ W_emb + b_emb)); jk = h0.
__global__ void __launch_bounds__(256) k_embed_hist(
    const float* __restrict__ x, const f16* __restrict__ Wh, const float* __restrict__ b,
    const float* __restrict__ lnw, const float* __restrict__ lnb,
    float* __restrict__ h, float* __restrict__ jk,
    const int* __restrict__ dst, int* __restrict__ deg, unsigned short* __restrict__ rank) {
    __shared__ f16 sxh[kTN * kFin];       // 8 KB
    __shared__ f16 sWh[kFin / 8 * kC * 8];// 16 KB, [i8][c] blocks of 8 halves
    int t = threadIdx.x;
    if (blockIdx.x < kHistGS) {           // ---- hist role (grid-stride, 4-deep)
        const int stride = kHistGS * 256;
        int e = blockIdx.x * 256 + t;
        for (; e + 3 * stride < kNE; e += 4 * stride) {
            int d0 = dst[e], d1 = dst[e + stride], d2 = dst[e + 2 * stride], d3 = dst[e + 3 * stride];
            int r0 = atomicAdd(&deg[d0], 1);
            int r1 = atomicAdd(&deg[d1], 1);
            int r2 = atomicAdd(&deg[d2], 1);
            int r3 = atomicAdd(&deg[d3], 1);
            rank[e] = (unsigned short)r0;
            rank[e + stride] = (unsigned short)r1;
            rank[e + 2 * stride] = (unsigned short)r2;
            rank[e + 3 * stride] = (unsigned short)r3;
        }
        for (; e < kNE; e += stride) {
            int d = dst[e];
            rank[e] = (unsigned short)atomicAdd(&deg[d], 1);
        }
        return;
    }
    // ---- embed role
    int n0 = (blockIdx.x - kHistGS) * kTN;       // 50000 = 3125 * 16 exact
    {
        const h8* Wg = (const h8*)Wh;
        h8* sW8 = (h8*)sWh;
        for (int i = t; i < kFin * kC / 8; i += 256) sW8[i] = Wg[i];
    }
    const float4* xg4 = (const float4*)(x + (long)n0 * kFin);
    f16x4* sx4 = (f16x4*)sxh;
    for (int i = t; i < kTN * kFin / 4; i += 256) {   // float4 loads: 4 iters/thread
        float4 v = xg4[i];
        f16x4 hv; hv.x = (f16)v.x; hv.y = (f16)v.y; hv.z = (f16)v.z; hv.w = (f16)v.w;
        sx4[i] = hv;
    }
    __syncthreads();
    int c = t & 31, n2 = t >> 5;          // n2 = 0..7
    const h8* xa = (const h8*)(sxh + n2 * kFin);
    const h8* xb = (const h8*)(sxh + (n2 + 8) * kFin);
    const h8* wr = (const h8*)sWh;        // [i8*kC + c]
    float a0 = 0.f, a0b = 0.f, a1 = 0.f, a1b = 0.f;
    #pragma unroll 8
    for (int i8 = 0; i8 < kFin / 8; ++i8) {
        h8 xv0 = xa[i8];
        h8 xv1 = xb[i8];
        h8 wv  = wr[i8 * kC + c];
        a0  = fdot2_(xv0.v[0], wv.v[0], a0);
        a0b = fdot2_(xv0.v[1], wv.v[1], a0b);
        a0  = fdot2_(xv0.v[2], wv.v[2], a0);
        a0b = fdot2_(xv0.v[3], wv.v[3], a0b);
        a1  = fdot2_(xv1.v[0], wv.v[0], a1);
        a1b = fdot2_(xv1.v[1], wv.v[1], a1b);
        a1  = fdot2_(xv1.v[2], wv.v[2], a1);
        a1b = fdot2_(xv1.v[3], wv.v[3], a1b);
    }
    float acc0 = a0 + a0b, acc1 = a1 + a1b;
    float bc = b[c], lw = lnw[c], lb = lnb[c];
    {
        float y = acc0 + bc;
        float m = y;
        #pragma unroll
        for (int o = 1; o < 32; o <<= 1) m += __shfl_xor(m, o);
        m *= (1.f / kC);
        float xc = y - m, v = xc * xc;
        #pragma unroll
        for (int o = 1; o < 32; o <<= 1) v += __shfl_xor(v, o);
        v *= (1.f / kC);
        float out = fmaxf(xc * rsqrtf(v + kEps) * lw + lb, 0.f);
        int node = n0 + n2;
        h[node * kC + c] = out;
        jk[node * kC + c] = out;
    }
    {
        float y = acc1 + bc;
        float m = y;
        #pragma unroll
        for (int o = 1; o < 32; o <<= 1) m += __shfl_xor(m, o);
        m *= (1.f / kC);
        float xc = y - m, v = xc * xc;
        #pragma unroll
        for (int o = 1; o < 32; o <<= 1) v += __shfl_xor(v, o);
        v *= (1.f / kC);
        float out = fmaxf(xc * rsqrtf(v + kEps) * lw + lb, 0.f);
        int node = n0 + n2 + 8;
        h[node * kC + c] = out;
        jk[node * kC + c] = out;
    }
}

// ---- trans body: xl = h@Wl + bl (fp16) ; xr = h@Wr + br (fp32). bid = node-tile idx.
__device__ __forceinline__ void trans_body(
    int bid, float* s_h, const float* __restrict__ h,
    const float* __restrict__ Wl, const float* __restrict__ bl,
    const float* __restrict__ Wr, const float* __restrict__ br,
    __half* __restrict__ xl, float* __restrict__ xr) {
    int t = threadIdx.x;
    int j = t & 127, hf = t >> 7;
    float wl[kC], wr[kC];
    #pragma unroll
    for (int k = 0; k < kC; ++k) { wl[k] = Wl[k * kHC + j]; wr[k] = Wr[k * kHC + j]; }
    float blj = bl[j], brj = br[j];
    int n0 = bid * 32;
    int nn = min(32, kNodes - n0);
    for (int i = t; i < nn * kC; i += 256) s_h[i] = h[n0 * kC + i];
    __syncthreads();
    int nend = min(nn, hf * 16 + 16);
    for (int n = hf * 16; n < nend; ++n) {
        const float4* h4 = (const float4*)(s_h + n * kC);
        float al = blj, ar = brj;
        #pragma unroll
        for (int kq = 0; kq < 8; ++kq) {
            float4 hv = h4[kq];
            al += hv.x * wl[kq*4] + hv.y * wl[kq*4+1] + hv.z * wl[kq*4+2] + hv.w * wl[kq*4+3];
            ar += hv.x * wr[kq*4] + hv.y * wr[kq*4+1] + hv.z * wr[kq*4+2] + hv.w * wr[kq*4+3];
        }
        long g = (long)(n0 + n) * kHC + j;
        xl[g] = __float2half(al);
        xr[g] = ar;
    }
}

// ---- K_B: role-split fused kernel (layer 0 only).
// blocks [0, kReoGS): reorder, atomic-free, grid-stride 4-deep.
// blocks [kReoGS, +kTransBlocks): trans layer 0 (needs only h).
__global__ void __launch_bounds__(256) k_trans_reorder(
    const float* __restrict__ h,
    const float* __restrict__ Wl, const float* __restrict__ bl,
    const float* __restrict__ Wr, const float* __restrict__ br,
    __half* __restrict__ xl, float* __restrict__ xr,
    const int* __restrict__ src, const int* __restrict__ dst, const float* __restrict__ ea,
    const int* __restrict__ rowptr, const unsigned short* __restrict__ rank,
    int2* __restrict__ epack) {
    __shared__ float s_h[32 * kC];
    if (blockIdx.x < kReoGS) {            // ---- reorder role (starts first)
        const int stride = kReoGS * 256;
        int e = blockIdx.x * 256 + threadIdx.x;
        for (; e + 3 * stride < kNE; e += 4 * stride) {
            int e1 = e + stride, e2 = e + 2 * stride, e3 = e + 3 * stride;
            int d0 = dst[e], d1 = dst[e1], d2 = dst[e2], d3 = dst[e3];
            int r0 = rank[e], r1 = rank[e1], r2 = rank[e2], r3 = rank[e3];
            int p0 = rowptr[d0] + r0, p1 = rowptr[d1] + r1;
            int p2 = rowptr[d2] + r2, p3 = rowptr[d3] + r3;
            epack[p0] = make_int2(src[e],  __float_as_int(ea[e]));
            epack[p1] = make_int2(src[e1], __float_as_int(ea[e1]));
            epack[p2] = make_int2(src[e2], __float_as_int(ea[e2]));
            epack[p3] = make_int2(src[e3], __float_as_int(ea[e3]));
        }
        for (; e < kNE; e += stride) {
            int d = dst[e];
            int pos = rowptr[d] + (int)rank[e];
            epack[pos] = make_int2(src[e], __float_as_int(ea[e]));
        }
        return;
    }
    trans_body(blockIdx.x - kReoGS, s_h, h, Wl, bl, Wr, br, xl, xr);
}

// ---- CSR scans (parallel 3-dispatch version; single-block scan was 76 µs —
// one CU has no MLP to hide 50k load round-trips. Dispatch overhead << that.)
__global__ void __launch_bounds__(256) k_scan1(const int* __restrict__ deg,
                                               int* __restrict__ excl, int* __restrict__ bsum) {
    __shared__ int s[256];
    int t = threadIdx.x;
    int i = blockIdx.x * 256 + t;
    int v = (i < kNodes) ? deg[i] : 0;
    s[t] = v;
    __syncthreads();
    for (int o = 1; o < 256; o <<= 1) {
        int tv = (t >= o) ? s[t - o] : 0;
        __syncthreads();
        s[t] += tv;
        __syncthreads();
    }
    if (i < kNodes) excl[i] = s[t] - v;
    if (t == 255) bsum[blockIdx.x] = s[255];
}

__global__ void __launch_bounds__(256) k_scan2(int* __restrict__ bsum, int nb) {
    __shared__ int s[256];
    int t = threadIdx.x;
    int v = (t < nb) ? bsum[t] : 0;
    s[t] = v;
    __syncthreads();
    for (int o = 1; o < 256; o <<= 1) {
        int tv = (t >= o) ? s[t - o] : 0;
        __syncthreads();
        s[t] += tv;
        __syncthreads();
    }
    if (t < nb) bsum[t] = s[t];
}

__global__ void __launch_bounds__(256) k_scan3(int* __restrict__ excl, const int* __restrict__ bsum) {
    int i = blockIdx.x * 256 + threadIdx.x;
    if (i >= kNodes) return;
    if (blockIdx.x > 0) excl[i] += bsum[blockIdx.x - 1];
}

// ---- batched edge processing: U pairs (2U edges), loads issued before use.
struct h4 { __half2 a, b; };              // 8 B = 4 halves
template<int U>
__device__ __forceinline__ void gat_batch(
    const int2* __restrict__ epack, int base2, bool slot0, int f,
    const h4* __restrict__ xl4, float4 Wev, float4 xrv, float4 av,
    float& l, float& o0, float& o1, float& o2, float& o3) {
    int2 pa[U], pb[U];
    #pragma unroll
    for (int u = 0; u < U; ++u) {
        pa[u] = epack[base2 + 2 * u];
        pb[u] = epack[base2 + 2 * u + 1];
    }
    h4 xv[U]; float eav[U];
    #pragma unroll
    for (int u = 0; u < U; ++u) {
        int srow = slot0 ? pa[u].x : pb[u].x;
        xv[u] = xl4[(long)srow * 32 + f];
        eav[u] = __int_as_float(slot0 ? pa[u].y : pb[u].y);
    }
    #pragma unroll
    for (int u = 0; u < U; ++u) {
        float2 x01 = __half22float2(xv[u].a), x23 = __half22float2(xv[u].b);
        float a0 = fmaf(eav[u], Wev.x, xrv.x) + x01.x;
        float a1 = fmaf(eav[u], Wev.y, xrv.y) + x01.y;
        float a2 = fmaf(eav[u], Wev.z, xrv.z) + x23.x;
        float a3 = fmaf(eav[u], Wev.w, xrv.w) + x23.y;
        a0 = fmaxf(a0, kSlope * a0); a1 = fmaxf(a1, kSlope * a1);
        a2 = fmaxf(a2, kSlope * a2); a3 = fmaxf(a3, kSlope * a3);
        float pp = red8(a0 * av.x + a1 * av.y + a2 * av.z + a3 * av.w);
        float eu = __builtin_amdgcn_exp2f(pp - kShift2);
        l += eu;
        o0 = fmaf(eu, x01.x, o0); o1 = fmaf(eu, x01.y, o1);
        o2 = fmaf(eu, x23.x, o2); o3 = fmaf(eu, x23.y, o3);
    }
}

// ---- K3: fused edge phase, 4 features/lane, 2 edges/wave, 1 wave/node.
__global__ void __launch_bounds__(256) k_edge(
    const int* __restrict__ rowptr, const int* __restrict__ deg,
    const int2* __restrict__ epack,
    const __half* __restrict__ xl, float* __restrict__ xrg,
    const float* __restrict__ We, const float* __restrict__ att,
    const float* __restrict__ gat_b, float* __restrict__ ps, float* __restrict__ pq) {
    int t = threadIdx.x & 63;
    int w = __builtin_amdgcn_readfirstlane(threadIdx.x >> 6);   // wave 0..3 (uniform)
    int d = blockIdx.x * 4 + w;           // node (50000 = 12500 * 4 exact)
    int f = t & 31;                       // feature quad
    bool slot0 = (t < 32);
    float em0 = slot0 ? 1.f : 0.f;

    const h4* xl4 = (const h4*)xl;        // row stride 32 h4
    long rowq = (long)d * 32;

    float4 xrv = ((const float4*)xrg)[rowq + f];
    float4 Wev = ((const float4*)We)[f];
    float4 av  = ((const float4*)att)[f];
    av.x *= kL2E; av.y *= kL2E; av.z *= kL2E; av.w *= kL2E;
    float4 gb  = ((const float4*)gat_b)[f];

    h4 xs = xl4[rowq + f];
    float2 xs01 = __half22float2(xs.a), xs23 = __half22float2(xs.b);

    // self loop (ea = 0), counted on slot 0 only
    float z0 = xs01.x + xrv.x, z1 = xs01.y + xrv.y;
    float z2 = xs23.x + xrv.z, z3 = xs23.y + xrv.w;
    z0 = fmaxf(z0, kSlope * z0); z1 = fmaxf(z1, kSlope * z1);
    z2 = fmaxf(z2, kSlope * z2); z3 = fmaxf(z3, kSlope * z3);
    float p = red8(z0 * av.x + z1 * av.y + z2 * av.z + z3 * av.w);
    float ee = __builtin_amdgcn_exp2f(p - kShift2) * em0;
    float l = ee;
    float o0 = ee * xs01.x, o1 = ee * xs01.y, o2 = ee * xs23.x, o3 = ee * xs23.y;

    int base = rowptr[d], cnt = deg[d];   // uniform -> SGPR
    int npair = cnt >> 1;
    int e = 0;
    for (; e + 8 <= npair; e += 8)
        gat_batch<8>(epack, base + 2 * e, slot0, f, xl4, Wev, xrv, av, l, o0, o1, o2, o3);
    if (e + 4 <= npair) {
        gat_batch<4>(epack, base + 2 * e, slot0, f, xl4, Wev, xrv, av, l, o0, o1, o2, o3);
        e += 4;
    }
    for (; e < npair; ++e)
        gat_batch<1>(epack, base + 2 * e, slot0, f, xl4, Wev, xrv, av, l, o0, o1, o2, o3);
    if (cnt & 1) {                        // odd tail edge on slot 0 only
        int2 ep = epack[base + cnt - 1];
        int srow = ep.x;
        float eav = __int_as_float(ep.y);
        h4 xv = xl4[(long)srow * 32 + f];
        float2 x01 = __half22float2(xv.a), x23 = __half22float2(xv.b);
        float a0 = fmaf(eav, Wev.x, xrv.x) + x01.x;
        float a1 = fmaf(eav, Wev.y, xrv.y) + x01.y;
        float a2 = fmaf(eav, Wev.z, xrv.z) + x23.x;
        float a3 = fmaf(eav, Wev.w, xrv.w) + x23.y;
        a0 = fmaxf(a0, kSlope * a0); a1 = fmaxf(a1, kSlope * a1);
        a2 = fmaxf(a2, kSlope * a2); a3 = fmaxf(a3, kSlope * a3);
        float pp = red8(a0 * av.x + a1 * av.y + a2 * av.z + a3 * av.w);
        float eu = __builtin_amdgcn_exp2f(pp - kShift2) * em0;
        l += eu;
        o0 = fmaf(eu, x01.x, o0); o1 = fmaf(eu, x01.y, o1);
        o2 = fmaf(eu, x23.x, o2); o3 = fmaf(eu, x23.y, o3);
    }
    // merge the two edge slots
    l  += __shfl_xor(l, 32);
    o0 += __shfl_xor(o0, 32); o1 += __shfl_xor(o1, 32);
    o2 += __shfl_xor(o2, 32); o3 += __shfl_xor(o3, 32);
    float rl = __builtin_amdgcn_rcpf(l);
    float v0 = o0 * rl, v1 = o1 * rl, v2 = o2 * rl, v3 = o3 * rl;
    if (slot0)
        ((float4*)xrg)[rowq + f] = make_float4(v0, v1, v2, v3);  // g overwrites xr
    float vb0 = v0 + gb.x, vb1 = v1 + gb.y, vb2 = v2 + gb.z, vb3 = v3 + gb.w;
    float s = vb0 + vb1 + vb2 + vb3;
    float q = vb0 * vb0 + vb1 * vb1 + vb2 * vb2 + vb3 * vb3;
    #pragma unroll
    for (int mm = 1; mm < 32; mm <<= 1) { s += __shfl_xor(s, mm); q += __shfl_xor(q, mm); }
    if (t == 0) { ps[d] = s; pq[d] = q; }
}

// ---- K4: reduce per-node partials -> stats[2]. 8 blocks + atomic finish
// (stats zeroed once in k_prep; per-layer stats slot).
__global__ void __launch_bounds__(1024) k_statsr(
    const float* __restrict__ ps, const float* __restrict__ pq, float* __restrict__ stats) {
    __shared__ float rs[1024], rq[1024];
    int t = threadIdx.x;
    float s = 0.f, q = 0.f;
    for (int i = blockIdx.x * 1024 + t; i < kNodes; i += 8 * 1024) { s += ps[i]; q += pq[i]; }
    rs[t] = s; rq[t] = q;
    __syncthreads();
    for (int o = 512; o > 0; o >>= 1) {
        if (t < o) { rs[t] += rs[t + o]; rq[t] += rq[t + o]; }
        __syncthreads();
    }
    if (t == 0) { atomicAdd(&stats[0], rs[0]); atomicAdd(&stats[1], rq[0]); }
}

// ---- K5: out = relu(node_ln(relu(graph_ln(g+gat_b)) @ lin_w + lin_b));
// jk_out = max(jk_in, out). If do_trans: next layer's xl/xr computed in-kernel.
// Trans weights are re-staged as f16x2 into the DEAD s_lwT LDS region after
// the GEMM phase (R12 post-mortem: VGPR=48 forced per-thread GLOBAL weight
// reloads in the trans loop; LDS column reads are conflict-free b32).
__global__ void __launch_bounds__(256) k_post(
    const float* __restrict__ g, const float* __restrict__ gat_b,
    const float* __restrict__ ln1w, const float* __restrict__ ln1b,
    const float* __restrict__ linw, const float* __restrict__ linb,
    const float* __restrict__ ln2w, const float* __restrict__ ln2b,
    const float* __restrict__ stats, const float* __restrict__ jk_in,
    float* __restrict__ jk_out, int do_trans,
    const float* __restrict__ Wl, const float* __restrict__ bl,
    const float* __restrict__ Wr, const float* __restrict__ br,
    __half* __restrict__ xl, float* __restrict__ xr) {
    __shared__ float s_lwT[kC * kLWP];    // 16.6 KB; reused as f16x2 Wl/Wr cache in trans phase
    __shared__ float s_vb[8 * kHC];       // 4 KB
    __shared__ float s_hh[8 * kC];        // 1 KB, this block's out-tile
    int t = threadIdx.x;
    int n0 = blockIdx.x * 8;
    int j = t & 127;
    const float inv = 1.f / ((float)kNodes * kHC);
    float mean = stats[0] * inv;
    float var  = stats[1] * inv - mean * mean;
    float rstd = rsqrtf(var + kEps);
    for (int i = t; i < kHC * kC; i += 256) {
        int k = i >> 5, c = i & 31;
        s_lwT[c * kLWP + k] = linw[i];
    }
    for (int i = t; i < 8 * kHC; i += 256) {
        int node = n0 + (i >> 7), f = i & 127;
        float a = (g[(long)node * kHC + f] + gat_b[f] - mean) * rstd * ln1w[f] + ln1b[f];
        s_vb[i] = fmaxf(a, 0.f);
    }
    __syncthreads();
    int n = t >> 5, c = t & 31;
    int node = n0 + n;
    float acc = linb[c];
    const float* vb = s_vb + n * kHC;
    const float* wrt = s_lwT + c * kLWP;
    #pragma unroll 8
    for (int k = 0; k < kHC; k += 4) {
        float4 v4 = *(const float4*)(vb + k);
        float2 w0 = *(const float2*)(wrt + k);
        float2 w1 = *(const float2*)(wrt + k + 2);
        acc += v4.x * w0.x + v4.y * w0.y + v4.z * w1.x + v4.w * w1.y;
    }
    float m = acc;
    #pragma unroll
    for (int mm = 1; mm < 32; mm <<= 1) m += __shfl_xor(m, mm);
    m *= (1.f / kC);
    float dd = acc - m;
    float q = dd * dd;
    #pragma unroll
    for (int mm = 1; mm < 32; mm <<= 1) q += __shfl_xor(q, mm);
    q *= (1.f / kC);
    float out = dd * rsqrtf(q + kEps) * ln2w[c] + ln2b[c];
    out = fmaxf(out, 0.f);
    jk_out[node * kC + c] = fmaxf(jk_in[node * kC + c], out);
    if (!do_trans) return;
    s_hh[n * kC + c] = out;
    __syncthreads();                       // GEMM reads of s_lwT done; s_hh visible
    // ---- re-stage Wl|Wr as f16x2 into the dead s_lwT region (coalesced)
    f16x2* w2 = (f16x2*)s_lwT;            // kC*kHC = 4096 f16x2 = 16 KB
    for (int i = t; i < kC * kHC; i += 256) {
        f16x2 pw; pw.x = (f16)Wl[i]; pw.y = (f16)Wr[i];
        w2[i] = pw;
    }
    __syncthreads();
    // per-thread: pull column j (32 conflict-free ds_read_b32), convert once
    float wl[kC], wr[kC];
    #pragma unroll
    for (int k = 0; k < kC; ++k) {
        f16x2 pw = w2[k * kHC + j];
        wl[k] = (float)pw.x; wr[k] = (float)pw.y;
    }
    int hf = t >> 7;
    float blj = bl[j], brj = br[j];
    #pragma unroll
    for (int nn2 = 0; nn2 < 4; ++nn2) {
        int nn = hf * 4 + nn2;
        const float4* h4p = (const float4*)(s_hh + nn * kC);
        float al = blj, ar = brj;
        #pragma unroll
        for (int kq = 0; kq < 8; ++kq) {
            float4 hv = h4p[kq];
            al += hv.x * wl[kq*4] + hv.y * wl[kq*4+1] + hv.z * wl[kq*4+2] + hv.w * wl[kq*4+3];
            ar += hv.x * wr[kq*4] + hv.y * wr[kq*4+1] + hv.z * wr[kq*4+2] + hv.w * wr[kq*4+3];
        }
        long gg = (long)(n0 + nn) * kHC + j;
        xl[gg] = __float2half(al);
        xr[gg] = ar;
    }
}

extern "C" void kernel_launch(void* const* d_in, const int* in_sizes, int n_in,
                              void* d_out, int out_size, void* d_ws, size_t ws_size,
                              hipStream_t stream) {
    (void)in_sizes; (void)n_in; (void)out_size; (void)ws_size;
    const float* x     = (const float*)d_in[0];
    const int*   ei    = (const int*)d_in[1];
    const int*   src   = ei;
    const int*   dst   = ei + kNE;
    const float* ea    = (const float*)d_in[2];
    const float* W_emb = (const float*)d_in[3];
    const float* b_emb = (const float*)d_in[4];
    const float* ln0w  = (const float*)d_in[5];
    const float* ln0b  = (const float*)d_in[6];
    const float* Wl    = (const float*)d_in[7];
    const float* bl    = (const float*)d_in[8];
    const float* Wr    = (const float*)d_in[9];
    const float* br    = (const float*)d_in[10];
    const float* We    = (const float*)d_in[11];
    const float* att   = (const float*)d_in[12];
    const float* gat_b = (const float*)d_in[13];
    const float* ln1w  = (const float*)d_in[14];
    const float* ln1b  = (const float*)d_in[15];
    const float* linw  = (const float*)d_in[16];
    const float* linb  = (const float*)d_in[17];
    const float* ln2w  = (const float*)d_in[18];
    const float* ln2b  = (const float*)d_in[19];

    char* wsb = (char*)d_ws;
    float*  h      = (float*)(wsb);                 // 6.4e6 B
    float*  jk     = (float*)(wsb +  6400000);      // 6.4e6 B
    float*  xrg    = (float*)(wsb + 12800000);      // 25.6e6 B (xr, later g)
    __half* xl     = (__half*)(wsb + 38400000);     // 12.8e6 B
    int2*   epack  = (int2*)(wsb + 51200000);       // 6.4e6 B (packed src+ea per edge)
    int*    deg    = (int*)(wsb + 57600000);        // 0.2e6 B
    int*    rowptr = (int*)(wsb + 58000000);        // 0.2e6 B
    int*    bsum   = (int*)(wsb + 58200000);        // 1 KB
    float*  stats  = (float*)(wsb + 58201024);      // 16 B (2 layers x 2)
    float*  ps     = (float*)(wsb + 58300000);      // 0.2e6 B
    float*  pq     = (float*)(wsb + 58500000);      // 0.2e6 B
    unsigned short* rank = (unsigned short*)(wsb + 58700000);  // 1.6e6 B
    f16*    Wh     = (f16*)(wsb + 60400000);        // 16 KB (pre-swizzled fp16 W_emb)

    const int scanBlocks = (kNodes + 255) / 256;         // 196
    const int edgeBlocks = kNodes / 4;                   // 12500 exact, 4 nodes/block
    const int postBlocks = kNodes / 8;                   // 6250 exact

    // prep: zero deg + stats, convert/swizzle W_emb -> fp16
    hipLaunchKernelGGL(k_prep, dim3(kDegBlocks + 32), dim3(256), 0, stream,
                       (unsigned*)deg, W_emb, Wh, stats);
    hipLaunchKernelGGL(k_embed_hist, dim3(kHistGS + kEmbedBlocks), dim3(256), 0, stream,
                       x, Wh, b_emb, ln0w, ln0b, h, jk, dst, deg, rank);
    hipLaunchKernelGGL(k_scan1, dim3(scanBlocks), dim3(256), 0, stream, deg, rowptr, bsum);
    hipLaunchKernelGGL(k_scan2, dim3(1), dim3(256), 0, stream, bsum, scanBlocks);
    hipLaunchKernelGGL(k_scan3, dim3(scanBlocks), dim3(256), 0, stream, rowptr, bsum);
    // fused reorder ∥ trans(layer 0)
    hipLaunchKernelGGL(k_trans_reorder, dim3(kReoGS + kTransBlocks), dim3(256), 0, stream,
                       h, Wl, bl, Wr, br, xl, xrg,
                       src, dst, ea, rowptr, rank, epack);
    for (int l = 0; l < 2; ++l) {
        hipLaunchKernelGGL(k_edge, dim3(edgeBlocks), dim3(256), 0, stream,
                           rowptr, deg, epack, xl, xrg,
                           We + l * kHC, att + l * kH * kC, gat_b + l * kHC, ps, pq);
        hipLaunchKernelGGL(k_statsr, dim3(8), dim3(1024), 0, stream, ps, pq, stats + 2 * l);
        // post: l=0 fuses next layer's trans (writes xl/xr); l=1 writes d_out
        hipLaunchKernelGGL(k_post, dim3(postBlocks), dim3(256), 0, stream,
                           xrg, gat_b + l * kHC, ln1w + l * kHC, ln1b + l * kHC,
                           linw + l * kHC * kC, linb + l * kC,
                           ln2w + l * kC, ln2b + l * kC, stats + 2 * l, jk,
                           (l == 1) ? (float*)d_out : jk,
                           (l == 0) ? 1 : 0,
                           Wl + kC * kHC, bl + kHC, Wr + kC * kHC, br + kHC,
                           xl, xrg);
    }
}

// Round 14
// 389.444 us; speedup vs baseline: 1.2462x; 1.0632x over previous
//
#include <hip/hip_runtime.h>
#include <hip/hip_fp16.h>

constexpr int kNodes = 50000;
constexpr int kNE    = 800000;            // edges before self loops
constexpr int kFin   = 256;
constexpr int kC     = 32;
constexpr int kH     = 4;
constexpr int kHC    = 128;               // kH * kC
constexpr int kTN    = 16;                // nodes per k_embed block
constexpr int kEmbedBlocks = kNodes / kTN;        // 3125
constexpr int kTransBlocks = (kNodes + 31) / 32;  // 1563
constexpr int kHistGS = 256;              // grid-stride hist blocks (4-deep atomic MLP)
constexpr int kReoGS  = 256;              // grid-stride reorder blocks
constexpr int kDegBlocks = (kNodes + 255) / 256;  // 196 (k_prep deg-zero role)
constexpr float kEps   = 1e-5f;
constexpr float kSlope = 0.2f;
constexpr float kL2E   = 1.44269504f;     // log2(e): fold into att so exp is 1 instr
constexpr float kShift2 = 8.0f * 1.44269504f; // softmax-invariant shift (exp2 domain)

typedef _Float16 f16;
typedef _Float16 f16x2 __attribute__((ext_vector_type(2)));
typedef _Float16 f16x4 __attribute__((ext_vector_type(4)));
struct alignas(16) h8 { f16x2 v[4]; };    // 8 halves = 16 B

__device__ __forceinline__ float fdot2_(f16x2 a, f16x2 b, float c) {
#if __has_builtin(__builtin_amdgcn_fdot2)
    return __builtin_amdgcn_fdot2(a, b, c, false);
#else
    return fmaf((float)a.x, (float)b.x, fmaf((float)a.y, (float)b.y, c));
#endif
}

// ---- DPP butterfly add: v += partner(v), pure VALU (no DS pipe).
template<int CTRL>
__device__ __forceinline__ float dpp_add(float v) {
    int x = __builtin_amdgcn_update_dpp(0, __float_as_int(v), CTRL, 0xF, 0xF, true);
    return v + __int_as_float(x);
}
// 8-lane sum (head = 8 lanes x 4 features): xor1, xor2, then row_half_mirror.
__device__ __forceinline__ float red8(float p) {
    p = dpp_add<0xB1>(p);
    p = dpp_add<0x4E>(p);
    p = dpp_add<0x141>(p);
    return p;
}

// ---- K0: prep — zero deg (196 blocks) + zero stats + convert W_emb (32 blocks)
// and lin_w both layers (32 blocks) to fp16 PRE-SWIZZLED [k8][c][8].
__global__ void __launch_bounds__(256) k_prep(
    unsigned* __restrict__ deg, const float* __restrict__ W, f16* __restrict__ Wh,
    const float* __restrict__ linw, f16* __restrict__ lwh, float* __restrict__ stats) {
    int t = threadIdx.x;
    if (blockIdx.x == 0 && t < 4) stats[t] = 0.f;
    if (blockIdx.x < kDegBlocks) {
        int i = blockIdx.x * 256 + t;
        if (i < kNodes) deg[i] = 0u;
        return;
    }
    int bi = blockIdx.x - kDegBlocks;
    if (bi < 32) {                         // W_emb: kFin*kC = 8192 elems
        int i = bi * 256 + t;
        int k = i >> 5, c = i & 31;
        Wh[((k >> 3) * kC + c) * 8 + (k & 7)] = (f16)W[i];
        return;
    }
    bi -= 32;                              // lin_w: 2 layers x kHC*kC = 8192 elems
    int i = bi * 256 + t;
    int l = i >> 12, il = i & 4095;
    int k = il >> 5, c = il & 31;
    lwh[l * 4096 + ((k >> 3) * kC + c) * 8 + (k & 7)] = (f16)linw[i];
}

// ---- K_A: role-split fused kernel, fp16 operands + v_dot2_f32_f16.
// blocks [0, kHistGS): grid-stride degree histogram, 4-deep batches; the
// atomicAdd RETURN VALUE is the edge's rank within its dst row -> rank[e].
// blocks [kHistGS, +kEmbedBlocks): h0 = relu(node_ln(x @ W_emb + b_emb)); jk = h0.
__global__ void __launch_bounds__(256) k_embed_hist(
    const float* __restrict__ x, const f16* __restrict__ Wh, const float* __restrict__ b,
    const float* __restrict__ lnw, const float* __restrict__ lnb,
    float* __restrict__ h, float* __restrict__ jk,
    const int* __restrict__ dst, int* __restrict__ deg, unsigned short* __restrict__ rank) {
    __shared__ f16 sxh[kTN * kFin];       // 8 KB
    __shared__ f16 sWh[kFin / 8 * kC * 8];// 16 KB, [i8][c] blocks of 8 halves
    int t = threadIdx.x;
    if (blockIdx.x < kHistGS) {           // ---- hist role (grid-stride, 4-deep)
        const int stride = kHistGS * 256;
        int e = blockIdx.x * 256 + t;
        for (; e + 3 * stride < kNE; e += 4 * stride) {
            int d0 = dst[e], d1 = dst[e + stride], d2 = dst[e + 2 * stride], d3 = dst[e + 3 * stride];
            int r0 = atomicAdd(&deg[d0], 1);
            int r1 = atomicAdd(&deg[d1], 1);
            int r2 = atomicAdd(&deg[d2], 1);
            int r3 = atomicAdd(&deg[d3], 1);
            rank[e] = (unsigned short)r0;
            rank[e + stride] = (unsigned short)r1;
            rank[e + 2 * stride] = (unsigned short)r2;
            rank[e + 3 * stride] = (unsigned short)r3;
        }
        for (; e < kNE; e += stride) {
            int d = dst[e];
            rank[e] = (unsigned short)atomicAdd(&deg[d], 1);
        }
        return;
    }
    // ---- embed role
    int n0 = (blockIdx.x - kHistGS) * kTN;       // 50000 = 3125 * 16 exact
    {
        const h8* Wg = (const h8*)Wh;
        h8* sW8 = (h8*)sWh;
        for (int i = t; i < kFin * kC / 8; i += 256) sW8[i] = Wg[i];
    }
    const float4* xg4 = (const float4*)(x + (long)n0 * kFin);
    f16x4* sx4 = (f16x4*)sxh;
    for (int i = t; i < kTN * kFin / 4; i += 256) {
        float4 v = xg4[i];
        f16x4 hv; hv.x = (f16)v.x; hv.y = (f16)v.y; hv.z = (f16)v.z; hv.w = (f16)v.w;
        sx4[i] = hv;
    }
    __syncthreads();
    int c = t & 31, n2 = t >> 5;          // n2 = 0..7
    const h8* xa = (const h8*)(sxh + n2 * kFin);
    const h8* xb = (const h8*)(sxh + (n2 + 8) * kFin);
    const h8* wr = (const h8*)sWh;        // [i8*kC + c]
    float a0 = 0.f, a0b = 0.f, a1 = 0.f, a1b = 0.f;
    #pragma unroll 8
    for (int i8 = 0; i8 < kFin / 8; ++i8) {
        h8 xv0 = xa[i8];
        h8 xv1 = xb[i8];
        h8 wv  = wr[i8 * kC + c];
        a0  = fdot2_(xv0.v[0], wv.v[0], a0);
        a0b = fdot2_(xv0.v[1], wv.v[1], a0b);
        a0  = fdot2_(xv0.v[2], wv.v[2], a0);
        a0b = fdot2_(xv0.v[3], wv.v[3], a0b);
        a1  = fdot2_(xv1.v[0], wv.v[0], a1);
        a1b = fdot2_(xv1.v[1], wv.v[1], a1b);
        a1  = fdot2_(xv1.v[2], wv.v[2], a1);
        a1b = fdot2_(xv1.v[3], wv.v[3], a1b);
    }
    float acc0 = a0 + a0b, acc1 = a1 + a1b;
    float bc = b[c], lw = lnw[c], lb = lnb[c];
    {
        float y = acc0 + bc;
        float m = y;
        #pragma unroll
        for (int o = 1; o < 32; o <<= 1) m += __shfl_xor(m, o);
        m *= (1.f / kC);
        float xc = y - m, v = xc * xc;
        #pragma unroll
        for (int o = 1; o < 32; o <<= 1) v += __shfl_xor(v, o);
        v *= (1.f / kC);
        float out = fmaxf(xc * rsqrtf(v + kEps) * lw + lb, 0.f);
        int node = n0 + n2;
        h[node * kC + c] = out;
        jk[node * kC + c] = out;
    }
    {
        float y = acc1 + bc;
        float m = y;
        #pragma unroll
        for (int o = 1; o < 32; o <<= 1) m += __shfl_xor(m, o);
        m *= (1.f / kC);
        float xc = y - m, v = xc * xc;
        #pragma unroll
        for (int o = 1; o < 32; o <<= 1) v += __shfl_xor(v, o);
        v *= (1.f / kC);
        float out = fmaxf(xc * rsqrtf(v + kEps) * lw + lb, 0.f);
        int node = n0 + n2 + 8;
        h[node * kC + c] = out;
        jk[node * kC + c] = out;
    }
}

// ---- trans body: xl = h@Wl + bl (fp16) ; xr = h@Wr + br (fp32). bid = node-tile idx.
__device__ __forceinline__ void trans_body(
    int bid, float* s_h, const float* __restrict__ h,
    const float* __restrict__ Wl, const float* __restrict__ bl,
    const float* __restrict__ Wr, const float* __restrict__ br,
    __half* __restrict__ xl, float* __restrict__ xr) {
    int t = threadIdx.x;
    int j = t & 127, hf = t >> 7;
    float wl[kC], wr[kC];
    #pragma unroll
    for (int k = 0; k < kC; ++k) { wl[k] = Wl[k * kHC + j]; wr[k] = Wr[k * kHC + j]; }
    float blj = bl[j], brj = br[j];
    int n0 = bid * 32;
    int nn = min(32, kNodes - n0);
    for (int i = t; i < nn * kC; i += 256) s_h[i] = h[n0 * kC + i];
    __syncthreads();
    int nend = min(nn, hf * 16 + 16);
    for (int n = hf * 16; n < nend; ++n) {
        const float4* h4 = (const float4*)(s_h + n * kC);
        float al = blj, ar = brj;
        #pragma unroll
        for (int kq = 0; kq < 8; ++kq) {
            float4 hv = h4[kq];
            al += hv.x * wl[kq*4] + hv.y * wl[kq*4+1] + hv.z * wl[kq*4+2] + hv.w * wl[kq*4+3];
            ar += hv.x * wr[kq*4] + hv.y * wr[kq*4+1] + hv.z * wr[kq*4+2] + hv.w * wr[kq*4+3];
        }
        long g = (long)(n0 + n) * kHC + j;
        xl[g] = __float2half(al);
        xr[g] = ar;
    }
}

// ---- K_B: role-split fused kernel (layer 0 only).
// blocks [0, kReoGS): reorder, atomic-free, grid-stride 4-deep.
// blocks [kReoGS, +kTransBlocks): trans layer 0 (needs only h).
__global__ void __launch_bounds__(256) k_trans_reorder(
    const float* __restrict__ h,
    const float* __restrict__ Wl, const float* __restrict__ bl,
    const float* __restrict__ Wr, const float* __restrict__ br,
    __half* __restrict__ xl, float* __restrict__ xr,
    const int* __restrict__ src, const int* __restrict__ dst, const float* __restrict__ ea,
    const int* __restrict__ rowptr, const unsigned short* __restrict__ rank,
    int2* __restrict__ epack) {
    __shared__ float s_h[32 * kC];
    if (blockIdx.x < kReoGS) {            // ---- reorder role (starts first)
        const int stride = kReoGS * 256;
        int e = blockIdx.x * 256 + threadIdx.x;
        for (; e + 3 * stride < kNE; e += 4 * stride) {
            int e1 = e + stride, e2 = e + 2 * stride, e3 = e + 3 * stride;
            int d0 = dst[e], d1 = dst[e1], d2 = dst[e2], d3 = dst[e3];
            int r0 = rank[e], r1 = rank[e1], r2 = rank[e2], r3 = rank[e3];
            int p0 = rowptr[d0] + r0, p1 = rowptr[d1] + r1;
            int p2 = rowptr[d2] + r2, p3 = rowptr[d3] + r3;
            epack[p0] = make_int2(src[e],  __float_as_int(ea[e]));
            epack[p1] = make_int2(src[e1], __float_as_int(ea[e1]));
            epack[p2] = make_int2(src[e2], __float_as_int(ea[e2]));
            epack[p3] = make_int2(src[e3], __float_as_int(ea[e3]));
        }
        for (; e < kNE; e += stride) {
            int d = dst[e];
            int pos = rowptr[d] + (int)rank[e];
            epack[pos] = make_int2(src[e], __float_as_int(ea[e]));
        }
        return;
    }
    trans_body(blockIdx.x - kReoGS, s_h, h, Wl, bl, Wr, br, xl, xr);
}

// ---- CSR scans (parallel 3-dispatch version)
__global__ void __launch_bounds__(256) k_scan1(const int* __restrict__ deg,
                                               int* __restrict__ excl, int* __restrict__ bsum) {
    __shared__ int s[256];
    int t = threadIdx.x;
    int i = blockIdx.x * 256 + t;
    int v = (i < kNodes) ? deg[i] : 0;
    s[t] = v;
    __syncthreads();
    for (int o = 1; o < 256; o <<= 1) {
        int tv = (t >= o) ? s[t - o] : 0;
        __syncthreads();
        s[t] += tv;
        __syncthreads();
    }
    if (i < kNodes) excl[i] = s[t] - v;
    if (t == 255) bsum[blockIdx.x] = s[255];
}

__global__ void __launch_bounds__(256) k_scan2(int* __restrict__ bsum, int nb) {
    __shared__ int s[256];
    int t = threadIdx.x;
    int v = (t < nb) ? bsum[t] : 0;
    s[t] = v;
    __syncthreads();
    for (int o = 1; o < 256; o <<= 1) {
        int tv = (t >= o) ? s[t - o] : 0;
        __syncthreads();
        s[t] += tv;
        __syncthreads();
    }
    if (t < nb) bsum[t] = s[t];
}

__global__ void __launch_bounds__(256) k_scan3(int* __restrict__ excl, const int* __restrict__ bsum) {
    int i = blockIdx.x * 256 + threadIdx.x;
    if (i >= kNodes) return;
    if (blockIdx.x > 0) excl[i] += bsum[blockIdx.x - 1];
}

// ---- batched edge processing: U pairs (2U edges), loads issued before use.
struct h4 { __half2 a, b; };              // 8 B = 4 halves
template<int U>
__device__ __forceinline__ void gat_batch(
    const int2* __restrict__ epack, int base2, bool slot0, int f,
    const h4* __restrict__ xl4, float4 Wev, float4 xrv, float4 av,
    float& l, float& o0, float& o1, float& o2, float& o3) {
    int2 pa[U], pb[U];
    #pragma unroll
    for (int u = 0; u < U; ++u) {
        pa[u] = epack[base2 + 2 * u];
        pb[u] = epack[base2 + 2 * u + 1];
    }
    h4 xv[U]; float eav[U];
    #pragma unroll
    for (int u = 0; u < U; ++u) {
        int srow = slot0 ? pa[u].x : pb[u].x;
        xv[u] = xl4[(long)srow * 32 + f];
        eav[u] = __int_as_float(slot0 ? pa[u].y : pb[u].y);
    }
    #pragma unroll
    for (int u = 0; u < U; ++u) {
        float2 x01 = __half22float2(xv[u].a), x23 = __half22float2(xv[u].b);
        float a0 = fmaf(eav[u], Wev.x, xrv.x) + x01.x;
        float a1 = fmaf(eav[u], Wev.y, xrv.y) + x01.y;
        float a2 = fmaf(eav[u], Wev.z, xrv.z) + x23.x;
        float a3 = fmaf(eav[u], Wev.w, xrv.w) + x23.y;
        a0 = fmaxf(a0, kSlope * a0); a1 = fmaxf(a1, kSlope * a1);
        a2 = fmaxf(a2, kSlope * a2); a3 = fmaxf(a3, kSlope * a3);
        float pp = red8(a0 * av.x + a1 * av.y + a2 * av.z + a3 * av.w);
        float eu = __builtin_amdgcn_exp2f(pp - kShift2);
        l += eu;
        o0 = fmaf(eu, x01.x, o0); o1 = fmaf(eu, x01.y, o1);
        o2 = fmaf(eu, x23.x, o2); o3 = fmaf(eu, x23.y, o3);
    }
}

// ---- K3: fused edge phase, 4 features/lane, 2 edges/wave, 1 wave/node.
__global__ void __launch_bounds__(256) k_edge(
    const int* __restrict__ rowptr, const int* __restrict__ deg,
    const int2* __restrict__ epack,
    const __half* __restrict__ xl, float* __restrict__ xrg,
    const float* __restrict__ We, const float* __restrict__ att,
    const float* __restrict__ gat_b, float* __restrict__ ps, float* __restrict__ pq) {
    int t = threadIdx.x & 63;
    int w = __builtin_amdgcn_readfirstlane(threadIdx.x >> 6);   // wave 0..3 (uniform)
    int d = blockIdx.x * 4 + w;           // node (50000 = 12500 * 4 exact)
    int f = t & 31;                       // feature quad
    bool slot0 = (t < 32);
    float em0 = slot0 ? 1.f : 0.f;

    const h4* xl4 = (const h4*)xl;        // row stride 32 h4
    long rowq = (long)d * 32;

    float4 xrv = ((const float4*)xrg)[rowq + f];
    float4 Wev = ((const float4*)We)[f];
    float4 av  = ((const float4*)att)[f];
    av.x *= kL2E; av.y *= kL2E; av.z *= kL2E; av.w *= kL2E;
    float4 gb  = ((const float4*)gat_b)[f];

    h4 xs = xl4[rowq + f];
    float2 xs01 = __half22float2(xs.a), xs23 = __half22float2(xs.b);

    // self loop (ea = 0), counted on slot 0 only
    float z0 = xs01.x + xrv.x, z1 = xs01.y + xrv.y;
    float z2 = xs23.x + xrv.z, z3 = xs23.y + xrv.w;
    z0 = fmaxf(z0, kSlope * z0); z1 = fmaxf(z1, kSlope * z1);
    z2 = fmaxf(z2, kSlope * z2); z3 = fmaxf(z3, kSlope * z3);
    float p = red8(z0 * av.x + z1 * av.y + z2 * av.z + z3 * av.w);
    float ee = __builtin_amdgcn_exp2f(p - kShift2) * em0;
    float l = ee;
    float o0 = ee * xs01.x, o1 = ee * xs01.y, o2 = ee * xs23.x, o3 = ee * xs23.y;

    int base = rowptr[d], cnt = deg[d];   // uniform -> SGPR
    int npair = cnt >> 1;
    int e = 0;
    for (; e + 8 <= npair; e += 8)
        gat_batch<8>(epack, base + 2 * e, slot0, f, xl4, Wev, xrv, av, l, o0, o1, o2, o3);
    if (e + 4 <= npair) {
        gat_batch<4>(epack, base + 2 * e, slot0, f, xl4, Wev, xrv, av, l, o0, o1, o2, o3);
        e += 4;
    }
    for (; e < npair; ++e)
        gat_batch<1>(epack, base + 2 * e, slot0, f, xl4, Wev, xrv, av, l, o0, o1, o2, o3);
    if (cnt & 1) {                        // odd tail edge on slot 0 only
        int2 ep = epack[base + cnt - 1];
        int srow = ep.x;
        float eav = __int_as_float(ep.y);
        h4 xv = xl4[(long)srow * 32 + f];
        float2 x01 = __half22float2(xv.a), x23 = __half22float2(xv.b);
        float a0 = fmaf(eav, Wev.x, xrv.x) + x01.x;
        float a1 = fmaf(eav, Wev.y, xrv.y) + x01.y;
        float a2 = fmaf(eav, Wev.z, xrv.z) + x23.x;
        float a3 = fmaf(eav, Wev.w, xrv.w) + x23.y;
        a0 = fmaxf(a0, kSlope * a0); a1 = fmaxf(a1, kSlope * a1);
        a2 = fmaxf(a2, kSlope * a2); a3 = fmaxf(a3, kSlope * a3);
        float pp = red8(a0 * av.x + a1 * av.y + a2 * av.z + a3 * av.w);
        float eu = __builtin_amdgcn_exp2f(pp - kShift2) * em0;
        l += eu;
        o0 = fmaf(eu, x01.x, o0); o1 = fmaf(eu, x01.y, o1);
        o2 = fmaf(eu, x23.x, o2); o3 = fmaf(eu, x23.y, o3);
    }
    // merge the two edge slots
    l  += __shfl_xor(l, 32);
    o0 += __shfl_xor(o0, 32); o1 += __shfl_xor(o1, 32);
    o2 += __shfl_xor(o2, 32); o3 += __shfl_xor(o3, 32);
    float rl = __builtin_amdgcn_rcpf(l);
    float v0 = o0 * rl, v1 = o1 * rl, v2 = o2 * rl, v3 = o3 * rl;
    if (slot0)
        ((float4*)xrg)[rowq + f] = make_float4(v0, v1, v2, v3);  // g overwrites xr
    float vb0 = v0 + gb.x, vb1 = v1 + gb.y, vb2 = v2 + gb.z, vb3 = v3 + gb.w;
    float s = vb0 + vb1 + vb2 + vb3;
    float q = vb0 * vb0 + vb1 * vb1 + vb2 * vb2 + vb3 * vb3;
    #pragma unroll
    for (int mm = 1; mm < 32; mm <<= 1) { s += __shfl_xor(s, mm); q += __shfl_xor(q, mm); }
    if (t == 0) { ps[d] = s; pq[d] = q; }
}

// ---- K4: reduce per-node partials -> stats[2]. 8 blocks + atomic finish.
__global__ void __launch_bounds__(1024) k_statsr(
    const float* __restrict__ ps, const float* __restrict__ pq, float* __restrict__ stats) {
    __shared__ float rs[1024], rq[1024];
    int t = threadIdx.x;
    float s = 0.f, q = 0.f;
    for (int i = blockIdx.x * 1024 + t; i < kNodes; i += 8 * 1024) { s += ps[i]; q += pq[i]; }
    rs[t] = s; rq[t] = q;
    __syncthreads();
    for (int o = 512; o > 0; o >>= 1) {
        if (t < o) { rs[t] += rs[t + o]; rq[t] += rq[t + o]; }
        __syncthreads();
    }
    if (t == 0) { atomicAdd(&stats[0], rs[0]); atomicAdd(&stats[1], rq[0]); }
}

// ---- K5: out = relu(node_ln(relu(graph_ln(g+gat_b)) @ lin_w + lin_b));
// jk_out = max(jk_in, out). Lin GEMM in fp16 via v_dot2_f32_f16 (f32 accum):
// weights pre-swizzled fp16 [k8][c][8] from k_prep (straight h8 stage), vb
// stored f16. Inner loop: 32 DS + 64 dot2 vs old 96 DS + 128 FMA.
// LDS overlay: [0,1K)=s_hh | [1K,9K)=s_lwh + [9K,11K)=s_vbh (GEMM) ->
// [1K,17K)=w2 f16x2 Wl|Wr cache (trans phase; GEMM regions dead).
__global__ void __launch_bounds__(256) k_post(
    const float* __restrict__ g, const float* __restrict__ gat_b,
    const float* __restrict__ ln1w, const float* __restrict__ ln1b,
    const f16* __restrict__ lwh, const float* __restrict__ linb,
    const float* __restrict__ ln2w, const float* __restrict__ ln2b,
    const float* __restrict__ stats, const float* __restrict__ jk_in,
    float* __restrict__ jk_out, int do_trans,
    const float* __restrict__ Wl, const float* __restrict__ bl,
    const float* __restrict__ Wr, const float* __restrict__ br,
    __half* __restrict__ xl, float* __restrict__ xr) {
    __shared__ __align__(16) char smem[17408];
    float* s_hh  = (float*)smem;          // 1 KB, out-tile (survives into trans)
    f16*   s_lwh = (f16*)(smem + 1024);   // 8 KB, fp16 lin_w [k8][c][8]
    f16*   s_vbh = (f16*)(smem + 9216);   // 2 KB, fp16 vb
    int t = threadIdx.x;
    int n0 = blockIdx.x * 8;
    int j = t & 127;
    const float inv = 1.f / ((float)kNodes * kHC);
    float mean = stats[0] * inv;
    float var  = stats[1] * inv - mean * mean;
    float rstd = rsqrtf(var + kEps);
    {
        const h8* Wg = (const h8*)lwh;
        h8* sW8 = (h8*)s_lwh;
        for (int i = t; i < kHC * kC / 8; i += 256) sW8[i] = Wg[i];
    }
    for (int i = t; i < 8 * kHC; i += 256) {
        int node = n0 + (i >> 7), f = i & 127;
        float a = (g[(long)node * kHC + f] + gat_b[f] - mean) * rstd * ln1w[f] + ln1b[f];
        s_vbh[i] = (f16)fmaxf(a, 0.f);
    }
    __syncthreads();
    int n = t >> 5, c = t & 31;
    int node = n0 + n;
    const h8* vb8 = (const h8*)(s_vbh + n * kHC);
    const h8* w8  = (const h8*)s_lwh;
    float a0 = 0.f, a0b = 0.f;
    #pragma unroll
    for (int k8 = 0; k8 < kHC / 8; ++k8) {
        h8 vv = vb8[k8];
        h8 wv = w8[k8 * kC + c];
        a0  = fdot2_(vv.v[0], wv.v[0], a0);
        a0b = fdot2_(vv.v[1], wv.v[1], a0b);
        a0  = fdot2_(vv.v[2], wv.v[2], a0);
        a0b = fdot2_(vv.v[3], wv.v[3], a0b);
    }
    float acc = linb[c] + a0 + a0b;
    float m = acc;
    #pragma unroll
    for (int mm = 1; mm < 32; mm <<= 1) m += __shfl_xor(m, mm);
    m *= (1.f / kC);
    float dd = acc - m;
    float q = dd * dd;
    #pragma unroll
    for (int mm = 1; mm < 32; mm <<= 1) q += __shfl_xor(q, mm);
    q *= (1.f / kC);
    float out = dd * rsqrtf(q + kEps) * ln2w[c] + ln2b[c];
    out = fmaxf(out, 0.f);
    jk_out[node * kC + c] = fmaxf(jk_in[node * kC + c], out);
    if (!do_trans) return;
    s_hh[n * kC + c] = out;
    __syncthreads();                       // GEMM reads done; s_hh visible
    // ---- re-stage Wl|Wr as f16x2 over the dead GEMM region (coalesced)
    f16x2* w2 = (f16x2*)(smem + 1024);    // kC*kHC = 4096 f16x2 = 16 KB
    for (int i = t; i < kC * kHC; i += 256) {
        f16x2 pw; pw.x = (f16)Wl[i]; pw.y = (f16)Wr[i];
        w2[i] = pw;
    }
    __syncthreads();
    float wl[kC], wr[kC];
    #pragma unroll
    for (int k = 0; k < kC; ++k) {
        f16x2 pw = w2[k * kHC + j];
        wl[k] = (float)pw.x; wr[k] = (float)pw.y;
    }
    int hf = t >> 7;
    float blj = bl[j], brj = br[j];
    #pragma unroll
    for (int nn2 = 0; nn2 < 4; ++nn2) {
        int nn = hf * 4 + nn2;
        const float4* h4p = (const float4*)(s_hh + nn * kC);
        float al = blj, ar = brj;
        #pragma unroll
        for (int kq = 0; kq < 8; ++kq) {
            float4 hv = h4p[kq];
            al += hv.x * wl[kq*4] + hv.y * wl[kq*4+1] + hv.z * wl[kq*4+2] + hv.w * wl[kq*4+3];
            ar += hv.x * wr[kq*4] + hv.y * wr[kq*4+1] + hv.z * wr[kq*4+2] + hv.w * wr[kq*4+3];
        }
        long gg = (long)(n0 + nn) * kHC + j;
        xl[gg] = __float2half(al);
        xr[gg] = ar;
    }
}

extern "C" void kernel_launch(void* const* d_in, const int* in_sizes, int n_in,
                              void* d_out, int out_size, void* d_ws, size_t ws_size,
                              hipStream_t stream) {
    (void)in_sizes; (void)n_in; (void)out_size; (void)ws_size;
    const float* x     = (const float*)d_in[0];
    const int*   ei    = (const int*)d_in[1];
    const int*   src   = ei;
    const int*   dst   = ei + kNE;
    const float* ea    = (const float*)d_in[2];
    const float* W_emb = (const float*)d_in[3];
    const float* b_emb = (const float*)d_in[4];
    const float* ln0w  = (const float*)d_in[5];
    const float* ln0b  = (const float*)d_in[6];
    const float* Wl    = (const float*)d_in[7];
    const float* bl    = (const float*)d_in[8];
    const float* Wr    = (const float*)d_in[9];
    const float* br    = (const float*)d_in[10];
    const float* We    = (const float*)d_in[11];
    const float* att   = (const float*)d_in[12];
    const float* gat_b = (const float*)d_in[13];
    const float* ln1w  = (const float*)d_in[14];
    const float* ln1b  = (const float*)d_in[15];
    const float* linw  = (const float*)d_in[16];
    const float* linb  = (const float*)d_in[17];
    const float* ln2w  = (const float*)d_in[18];
    const float* ln2b  = (const float*)d_in[19];

    char* wsb = (char*)d_ws;
    float*  h      = (float*)(wsb);                 // 6.4e6 B
    float*  jk     = (float*)(wsb +  6400000);      // 6.4e6 B
    float*  xrg    = (float*)(wsb + 12800000);      // 25.6e6 B (xr, later g)
    __half* xl     = (__half*)(wsb + 38400000);     // 12.8e6 B
    int2*   epack  = (int2*)(wsb + 51200000);       // 6.4e6 B (packed src+ea per edge)
    int*    deg    = (int*)(wsb + 57600000);        // 0.2e6 B
    int*    rowptr = (int*)(wsb + 58000000);        // 0.2e6 B
    int*    bsum   = (int*)(wsb + 58200000);        // 1 KB
    float*  stats  = (float*)(wsb + 58201024);      // 16 B (2 layers x 2)
    float*  ps     = (float*)(wsb + 58300000);      // 0.2e6 B
    float*  pq     = (float*)(wsb + 58500000);      // 0.2e6 B
    unsigned short* rank = (unsigned short*)(wsb + 58700000);  // 1.6e6 B
    f16*    Wh     = (f16*)(wsb + 60400000);        // 16 KB (pre-swizzled fp16 W_emb)
    f16*    lwh    = (f16*)(wsb + 60420000);        // 16 KB (pre-swizzled fp16 lin_w x2)

    const int scanBlocks = (kNodes + 255) / 256;         // 196
    const int edgeBlocks = kNodes / 4;                   // 12500 exact, 4 nodes/block
    const int postBlocks = kNodes / 8;                   // 6250 exact

    // prep: zero deg + stats, convert/swizzle W_emb + lin_w -> fp16
    hipLaunchKernelGGL(k_prep, dim3(kDegBlocks + 64), dim3(256), 0, stream,
                       (unsigned*)deg, W_emb, Wh, linw, lwh, stats);
    hipLaunchKernelGGL(k_embed_hist, dim3(kHistGS + kEmbedBlocks), dim3(256), 0, stream,
                       x, Wh, b_emb, ln0w, ln0b, h, jk, dst, deg, rank);
    hipLaunchKernelGGL(k_scan1, dim3(scanBlocks), dim3(256), 0, stream, deg, rowptr, bsum);
    hipLaunchKernelGGL(k_scan2, dim3(1), dim3(256), 0, stream, bsum, scanBlocks);
    hipLaunchKernelGGL(k_scan3, dim3(scanBlocks), dim3(256), 0, stream, rowptr, bsum);
    // fused reorder ∥ trans(layer 0)
    hipLaunchKernelGGL(k_trans_reorder, dim3(kReoGS + kTransBlocks), dim3(256), 0, stream,
                       h, Wl, bl, Wr, br, xl, xrg,
                       src, dst, ea, rowptr, rank, epack);
    for (int l = 0; l < 2; ++l) {
        hipLaunchKernelGGL(k_edge, dim3(edgeBlocks), dim3(256), 0, stream,
                           rowptr, deg, epack, xl, xrg,
                           We + l * kHC, att + l * kH * kC, gat_b + l * kHC, ps, pq);
        hipLaunchKernelGGL(k_statsr, dim3(8), dim3(1024), 0, stream, ps, pq, stats + 2 * l);
        // post: l=0 fuses next layer's trans (writes xl/xr); l=1 writes d_out
        hipLaunchKernelGGL(k_post, dim3(postBlocks), dim3(256), 0, stream,
                           xrg, gat_b + l * kHC, ln1w + l * kHC, ln1b + l * kHC,
                           lwh + l * kHC * kC, linb + l * kC,
                           ln2w + l * kC, ln2b + l * kC, stats + 2 * l, jk,
                           (l == 1) ? (float*)d_out : jk,
                           (l == 0) ? 1 : 0,
                           Wl + kC * kHC, bl + kHC, Wr + kC * kHC, br + kHC,
                           xl, xrg);
    }
}